// Round 4
// baseline (471.229 us; speedup 1.0000x reference)
//
#include <hip/hip_runtime.h>
#include <math.h>

#define B_    64
#define I_    512
#define C_    32
#define PRED_ 96
#define PL_   16
#define ST_   8
#define NH_   8
#define PN_   64
#define N_    2048

__device__ __forceinline__ float geluf(float x) {
    return 0.5f * x * (1.0f + erff(x * 0.70710678118654752f));
}
__device__ __forceinline__ float softplusf(float x) {
    return fmaxf(x, 0.0f) + log1pf(__expf(-fabsf(x)));
}

// ---------------------------------------------------------------- k_headphi
// head gate (wp) then phi patch means, fused; 64 blocks x 256 threads
__global__ void k_headphi(const float* __restrict__ s, const float* __restrict__ rw1,
                          const float* __restrict__ rb1, const float* __restrict__ rw2,
                          const float* __restrict__ rb2,
                          const float* __restrict__ P0, const float* __restrict__ P1,
                          const float* __restrict__ P2, const int* __restrict__ cyc,
                          float* __restrict__ wp, float* __restrict__ phis) {
    int b = blockIdx.x, t = threadIdx.x;
    __shared__ float part[8][32];
    __shared__ float smean[32];
    __shared__ float h[16];
    __shared__ float wpl[3];
    __shared__ float pm[I_];
    int c = t & 31, chunk = t >> 5;
    float acc = 0.f;
    for (int l = chunk * 64; l < chunk * 64 + 64; ++l)
        acc += s[((size_t)b * I_ + l) * C_ + c];
    part[chunk][c] = acc;
    __syncthreads();
    if (t < 32) {
        float v = 0.f;
#pragma unroll
        for (int i = 0; i < 8; ++i) v += part[i][t];
        smean[t] = v * (1.0f / I_);
    }
    __syncthreads();
    if (t < 16) {
        float a = rb1[t];
#pragma unroll
        for (int c2 = 0; c2 < 32; ++c2) a += smean[c2] * rw1[t * 32 + c2];
        h[t] = geluf(a);
    }
    __syncthreads();
    if (t == 0) {
        float lg[3], mx = -1e30f;
        for (int k = 0; k < 3; ++k) {
            float a = rb2[k];
            for (int j = 0; j < 16; ++j) a += h[j] * rw2[k * 16 + j];
            lg[k] = a; mx = fmaxf(mx, a);
        }
        float d = 0.f;
        for (int k = 0; k < 3; ++k) { lg[k] = __expf(lg[k] - mx); d += lg[k]; }
        float inv = 1.f / d;
        for (int k = 0; k < 3; ++k) { wpl[k] = lg[k] * inv; wp[b * 3 + k] = lg[k] * inv; }
    }
    __syncthreads();
    float p0 = wpl[0], p1 = wpl[1], p2 = wpl[2];
    int cy = cyc[b];
    for (int l = t; l < I_; l += 256) {
        float acc2 = 0.f;
        {
            int idx = (cy + l) % 24;
            const float4* r = (const float4*)(P0 + idx * 32);
            float s4 = 0.f;
#pragma unroll
            for (int i = 0; i < 8; ++i) { float4 v = r[i]; s4 += v.x + v.y + v.z + v.w; }
            acc2 += p0 * s4;
        }
        {
            int idx = (cy + l) % 168;
            const float4* r = (const float4*)(P1 + idx * 32);
            float s4 = 0.f;
#pragma unroll
            for (int i = 0; i < 8; ++i) { float4 v = r[i]; s4 += v.x + v.y + v.z + v.w; }
            acc2 += p1 * s4;
        }
        {
            int idx = (cy + l) % 336;
            const float4* r = (const float4*)(P2 + idx * 32);
            float s4 = 0.f;
#pragma unroll
            for (int i = 0; i < 8; ++i) { float4 v = r[i]; s4 += v.x + v.y + v.z + v.w; }
            acc2 += p2 * s4;
        }
        pm[l] = acc2 * (1.0f / 32.0f);
    }
    __syncthreads();
    if (t < PN_) {
        float sum = 0.f;
#pragma unroll
        for (int j = 0; j < 16; ++j) {
            int l = t * ST_ + j; if (l > 511) l = 511;
            sum += pm[l];
        }
        phis[b * PN_ + t] = sum * (1.0f / 16.0f);
    }
}

// ---------------------------------------------------------------- k_attn
// Single-pass unnormalized softmax; kk-split into NS parts (runtime).
// launch_bounds(256,4): VGPR cap 128 so qr[8]+cs[8] (64 regs) stay in VGPRs
// (at 64-cap the compiler spills cs to AGPRs: 3x instr on the accumulate).
__global__ void __launch_bounds__(256, 4) k_attn(
        const float* __restrict__ s, const int* __restrict__ cyc,
        const float* __restrict__ A0, const float* __restrict__ A1, const float* __restrict__ A2,
        const float* __restrict__ P0, const float* __restrict__ P1, const float* __restrict__ P2,
        float* __restrict__ pd, float* __restrict__ pcs, int NS, int klen) {
    int bx = blockIdx.x;
    int kh = bx % NS, qh = bx / NS;
    int l = qh * 256 + threadIdx.x;
    int k3 = blockIdx.y, b = blockIdx.z;
    const float* Atab; const float* Ptab; int Wk;
    if (k3 == 0)      { Atab = A0; Ptab = P0; Wk = 24;  }
    else if (k3 == 1) { Atab = A1; Ptab = P1; Wk = 168; }
    else              { Atab = A2; Ptab = P2; Wk = 336; }
    int idx = (cyc[b] + l) % Wk;
    float4 qr[8];
    {
        const float4* Ar = (const float4*)(Atab + idx * 32);
        const float4* Pr = (const float4*)(Ptab + idx * 32);
#pragma unroll
        for (int i = 0; i < 8; ++i) {
            float4 a = Ar[i], p = Pr[i];
            float4 q;
            q.x = softplusf(a.x) * __cosf(p.x);
            q.y = softplusf(a.y) * __cosf(p.y);
            q.z = softplusf(a.z) * __cosf(p.z);
            q.w = softplusf(a.w) * __cosf(p.w);
            qr[i] = q;
        }
    }
    const float4* sb = (const float4*)(s + ((size_t)b * I_ + kh * klen) * C_);
    const float rs = 0.17677669529663687f;  // 1/sqrt(32)
    float d = 0.f;
    float4 cs[8];
#pragma unroll
    for (int i = 0; i < 8; ++i) cs[i] = make_float4(0.f, 0.f, 0.f, 0.f);
#pragma unroll 4
    for (int kk = 0; kk < klen; ++kk) {
        const float4* srow = sb + kk * 8;
        float4 sv[8];
        float acc = 0.f;
#pragma unroll
        for (int i = 0; i < 8; ++i) {
            sv[i] = srow[i];
            acc += qr[i].x * sv[i].x + qr[i].y * sv[i].y + qr[i].z * sv[i].z + qr[i].w * sv[i].w;
        }
        float w = __expf(acc * rs);
        d += w;
#pragma unroll
        for (int i = 0; i < 8; ++i) {
            cs[i].x += w * sv[i].x; cs[i].y += w * sv[i].y;
            cs[i].z += w * sv[i].z; cs[i].w += w * sv[i].w;
        }
    }
    int h = k3 * NS + kh;
    pd[((size_t)h * B_ + b) * I_ + l] = d;
    float* outp = pcs + (((size_t)h * B_ + b) * C_) * I_ + l;
#pragma unroll
    for (int i = 0; i < 8; ++i) {
        outp[(size_t)(i * 4 + 0) * I_] = cs[i].x;
        outp[(size_t)(i * 4 + 1) * I_] = cs[i].y;
        outp[(size_t)(i * 4 + 2) * I_] = cs[i].z;
        outp[(size_t)(i * 4 + 3) * I_] = cs[i].w;
    }
}

// ---------------------------------------------------------------- k_combine
__global__ void k_combine(const float* __restrict__ s, const float* __restrict__ t,
                          const float* __restrict__ pd, const float* __restrict__ pcs,
                          const float* __restrict__ wp,
                          float* __restrict__ srow, float* __restrict__ trow, int NS) {
    int b = blockIdx.x, l0 = blockIdx.y * 32;
    int tt_ = threadIdx.x;
    __shared__ float st[32][33], tl[32][33];
    __shared__ float rw[3][32];
#pragma unroll
    for (int r = 0; r < 4; ++r) {
        int lin = r * 256 + tt_;
        int lq = lin >> 5, c = lin & 31;
        st[lq][c] = s[((size_t)b * I_ + l0 + lq) * C_ + c];
        tl[lq][c] = t[((size_t)b * I_ + l0 + lq) * C_ + c];
    }
    if (tt_ < 96) {
        int k3 = tt_ >> 5, lq = tt_ & 31;
        float d = 0.f;
        for (int kh = 0; kh < NS; ++kh)
            d += pd[((size_t)(k3 * NS + kh) * B_ + b) * I_ + l0 + lq];
        rw[k3][lq] = wp[b * 3 + k3] / d;
    }
    __syncthreads();
#pragma unroll
    for (int r = 0; r < 4; ++r) {
        int lin = r * 256 + tt_;
        int co = lin >> 5, lo = lin & 31;
        float sum = 0.f;
        for (int k3 = 0; k3 < 3; ++k3) {
            float v = 0.f;
            for (int kh = 0; kh < NS; ++kh)
                v += pcs[(((size_t)(k3 * NS + kh) * B_ + b) * C_ + co) * I_ + l0 + lo];
            sum += rw[k3][lo] * v;
        }
        size_t oi = ((size_t)(b * C_ + co)) * I_ + l0 + lo;
        srow[oi] = st[lo][co] + sum;
        trow[oi] = tl[lo][co];
    }
}

// ---------------------------------------------------------------- k_patch
__global__ void __launch_bounds__(256) k_patch(
        const float* __restrict__ srow, const float* __restrict__ phis,
        const float* __restrict__ Wqkv, const float* __restrict__ bqkv,
        const float* __restrict__ Wo, const float* __restrict__ bo,
        const float* __restrict__ alpha_p, float* __restrict__ sx) {
    int n = blockIdx.x, t = threadIdx.x;
    int p = t & 63, w = t >> 6;
    int b = n >> 5;
    __shared__ float spl[64][17];
    __shared__ float ql[64][17], kl[64][17], vl[64][17];
    __shared__ float blds[64][65];
    __shared__ float phil[64];
    __shared__ float wq[48][16];
    __shared__ float wo[16][16];
    __shared__ float o2l[64][17];
    float alpha = alpha_p[0];
    for (int i = t; i < 768; i += 256) wq[i >> 4][i & 15] = Wqkv[i];
    if (t < 256) wo[t >> 4][t & 15] = Wo[t];
    if (t < 64) phil[t] = phis[b * PN_ + t];
    const float* srn = srow + (size_t)n * I_;
#pragma unroll
    for (int jj = 0; jj < 4; ++jj) {
        int j = w * 4 + jj;
        int l = p * ST_ + j; if (l > 511) l = 511;
        spl[p][j] = srn[l];
    }
    __syncthreads();
#pragma unroll
    for (int oo = 0; oo < 12; ++oo) {
        int o = w * 12 + oo;
        float a = bqkv[o];
#pragma unroll
        for (int i2 = 0; i2 < 16; ++i2) a += spl[p][i2] * wq[o][i2];
        if (o < 16) ql[p][o] = a;
        else if (o < 32) kl[p][o - 16] = a;
        else vl[p][o - 32] = a;
    }
    float phit = phil[p];
#pragma unroll
    for (int jj = 0; jj < 16; ++jj) {
        int ss = w * 16 + jj;
        blds[p][ss] = alpha * __cosf(phit - phil[ss]);
    }
    __syncthreads();
    const float rs2 = 0.70710678118654752f;
#pragma unroll
    for (int hh = 0; hh < 2; ++hh) {
        int h = 2 * w + hh;
        float q0 = ql[p][2 * h], q1 = ql[p][2 * h + 1];
        float mh = -1e30f;
        for (int ss = 0; ss < 64; ++ss) {
            float sc = (q0 * kl[ss][2 * h] + q1 * kl[ss][2 * h + 1]) * rs2 + blds[p][ss];
            mh = fmaxf(mh, sc);
        }
        float dh = 0.f, o0 = 0.f, o1 = 0.f;
        for (int ss = 0; ss < 64; ++ss) {
            float sc = (q0 * kl[ss][2 * h] + q1 * kl[ss][2 * h + 1]) * rs2 + blds[p][ss];
            float wgt = __expf(sc - mh);
            dh += wgt; o0 += wgt * vl[ss][2 * h]; o1 += wgt * vl[ss][2 * h + 1];
        }
        float inv = 1.f / dh;
        o2l[p][2 * h] = o0 * inv; o2l[p][2 * h + 1] = o1 * inv;
    }
    __syncthreads();
    float* sxr = sx + ((size_t)n * PN_ + p) * PL_;
#pragma unroll
    for (int ii = 0; ii < 4; ++ii) {
        int i2 = w * 4 + ii;
        float a = bo[i2];
#pragma unroll
        for (int j = 0; j < 16; ++j) a += o2l[p][j] * wo[i2][j];
        sxr[i2] = geluf(spl[p][i2] + a);
    }
}

// ---------------------------------------------------------------- k_bn_stats
__global__ void k_bn_stats(const float* __restrict__ sx, float* __restrict__ bnpart) {
    int pn = blockIdx.x, chunk = blockIdx.y, t = threadIdx.x;
    __shared__ float r1[256], r2[256];
    int j4 = t & 3, nb = t >> 2;
    float s1 = 0.f, s2 = 0.f;
    for (int i = 0; i < 8; ++i) {
        int n = chunk * 512 + nb + i * 64;
        float4 v = *(const float4*)(sx + ((size_t)n * PN_ + pn) * PL_ + j4 * 4);
        s1 += v.x + v.y + v.z + v.w;
        s2 += v.x * v.x + v.y * v.y + v.z * v.z + v.w * v.w;
    }
    r1[t] = s1; r2[t] = s2;
    __syncthreads();
    for (int st = 128; st > 0; st >>= 1) {
        if (t < st) { r1[t] += r1[t + st]; r2[t] += r2[t + st]; }
        __syncthreads();
    }
    if (t == 0) {
        bnpart[(pn * 4 + chunk) * 2 + 0] = r1[0];
        bnpart[(pn * 4 + chunk) * 2 + 1] = r2[0];
    }
}

// ---------------------------------------------------------------- k_bn_apply
__global__ void k_bn_apply(float* __restrict__ sx, const float* __restrict__ bnpart,
                           const float* __restrict__ g, const float* __restrict__ bb) {
    int g4 = blockIdx.x * 256 + threadIdx.x;
    int pn = (g4 >> 2) & 63;
    float s1 = 0.f, s2 = 0.f;
#pragma unroll
    for (int ch = 0; ch < 4; ++ch) {
        s1 += bnpart[(pn * 4 + ch) * 2 + 0];
        s2 += bnpart[(pn * 4 + ch) * 2 + 1];
    }
    const float inv = 1.0f / (N_ * PL_);
    float mu = s1 * inv;
    float var = s2 * inv - mu * mu;
    float rstd = rsqrtf(var + 1e-5f);
    float gg = g[pn], bbv = bb[pn];
    float4* p = (float4*)sx + g4;
    float4 v = *p;
    v.x = (v.x - mu) * rstd * gg + bbv;
    v.y = (v.y - mu) * rstd * gg + bbv;
    v.z = (v.z - mu) * rstd * gg + bbv;
    v.w = (v.w - mu) * rstd * gg + bbv;
    *p = v;
}

// ---------------------------------------------------------------- k_gemm32
template <int ACT>
__global__ void __launch_bounds__(128) k_gemm32(const float* __restrict__ A,
                                                const float* __restrict__ W,
                                                const float* __restrict__ bias,
                                                float* __restrict__ Cout,
                                                int M, int Nn, int K) {
    __shared__ float at[32][36];
    __shared__ float wt[32][36];
    int bm = blockIdx.x * 32, bn = blockIdx.y * 32;
    int t = threadIdx.x;
    int lr = t >> 2, lk = (t & 3) * 8;
    int tm = (t & 15) * 2, tn = (t >> 4) * 4;
    float acc[2][4] = {};
    for (int k0 = 0; k0 < K; k0 += 32) {
        float4 a0 = *(const float4*)(A + (size_t)(bm + lr) * K + k0 + lk);
        float4 a1 = *(const float4*)(A + (size_t)(bm + lr) * K + k0 + lk + 4);
        float4 w0 = *(const float4*)(W + (size_t)(bn + lr) * K + k0 + lk);
        float4 w1 = *(const float4*)(W + (size_t)(bn + lr) * K + k0 + lk + 4);
        __syncthreads();
        at[lk + 0][lr] = a0.x; at[lk + 1][lr] = a0.y; at[lk + 2][lr] = a0.z; at[lk + 3][lr] = a0.w;
        at[lk + 4][lr] = a1.x; at[lk + 5][lr] = a1.y; at[lk + 6][lr] = a1.z; at[lk + 7][lr] = a1.w;
        wt[lk + 0][lr] = w0.x; wt[lk + 1][lr] = w0.y; wt[lk + 2][lr] = w0.z; wt[lk + 3][lr] = w0.w;
        wt[lk + 4][lr] = w1.x; wt[lk + 5][lr] = w1.y; wt[lk + 6][lr] = w1.z; wt[lk + 7][lr] = w1.w;
        __syncthreads();
#pragma unroll
        for (int kk = 0; kk < 32; ++kk) {
            float2 a2 = *(const float2*)&at[kk][tm];
            float4 w4 = *(const float4*)&wt[kk][tn];
            acc[0][0] += a2.x * w4.x; acc[0][1] += a2.x * w4.y;
            acc[0][2] += a2.x * w4.z; acc[0][3] += a2.x * w4.w;
            acc[1][0] += a2.y * w4.x; acc[1][1] += a2.y * w4.y;
            acc[1][2] += a2.y * w4.z; acc[1][3] += a2.y * w4.w;
        }
    }
#pragma unroll
    for (int i = 0; i < 2; ++i) {
#pragma unroll
        for (int j = 0; j < 4; ++j) {
            float v = acc[i][j] + bias[bn + tn + j];
            if (ACT) v = geluf(v);
            Cout[(size_t)(bm + tm + i) * Nn + bn + tn + j] = v;
        }
    }
}

// ---------------------------------------------------------------- k_rowmlp4
__global__ void k_rowmlp4(const float* __restrict__ g3, const float* __restrict__ W4,
                          const float* __restrict__ b4, float* __restrict__ sxf) {
    int n = blockIdx.x, t = threadIdx.x;  // 128 threads
    __shared__ float row[192];
    for (int j = t; j < 192; j += 128) row[j] = g3[(size_t)n * 192 + j];
    __syncthreads();
    if (t < 96) {
        float a = b4[t];
        const float* wr = W4 + t * 192;
#pragma unroll 4
        for (int j = 0; j < 192; ++j) a += row[j] * wr[j];
        sxf[(size_t)n * 96 + t] = a;
    }
}

// ---------------------------------------------------------------- k_u (+ fused low-pass)
__global__ void k_u(const float* __restrict__ u1, const float* __restrict__ ln1g,
                    const float* __restrict__ ln1b, const float* __restrict__ W6,
                    const float* __restrict__ b6, const float* __restrict__ ln2g,
                    const float* __restrict__ ln2b, const float* __restrict__ W7,
                    const float* __restrict__ b7, float* __restrict__ u2out) {
    int n = blockIdx.x, t = threadIdx.x;  // 192 threads
    __shared__ float a[192];
    __shared__ float red1[256], red2[256];
    __shared__ float c2[48];
    __shared__ float stat[2];
    __shared__ float u3l[96];
    __shared__ float cosb[5][96], sinb[5][96];
    __shared__ float coef[9];
    if (t < 96) {
#pragma unroll
        for (int k = 0; k < 5; ++k) {
            float sv, cv2;
            __sincosf(6.283185307179586f * (float)(k * t) / 96.0f, &sv, &cv2);
            cosb[k][t] = cv2; sinb[k][t] = sv;
        }
    }
    const float* ur = u1 + (size_t)n * 384;
    float av = 0.5f * (ur[2 * t] + ur[2 * t + 1]);
    red1[t] = av; red2[t] = av * av;
    if (t < 64) { red1[192 + t] = 0.f; red2[192 + t] = 0.f; }
    __syncthreads();
    for (int st = 128; st > 0; st >>= 1) {
        if (t < st) { red1[t] += red1[t + st]; red2[t] += red2[t + st]; }
        __syncthreads();
    }
    if (t == 0) {
        float mu = red1[0] * (1.0f / 192.0f);
        float var = red2[0] * (1.0f / 192.0f) - mu * mu;
        stat[0] = mu; stat[1] = rsqrtf(var + 1e-5f);
    }
    __syncthreads();
    a[t] = (av - stat[0]) * stat[1] * ln1g[t] + ln1b[t];
    __syncthreads();
    float bv = 0.f;
    if (t < 96) {
        bv = b6[t];
        const float* wr = W6 + t * 192;
#pragma unroll 4
        for (int j = 0; j < 192; ++j) bv += a[j] * wr[j];
    }
    __syncthreads();
    if (t < 96) red1[t] = bv;
    __syncthreads();
    float cv = 0.f;
    if (t < 48) cv = 0.5f * (red1[2 * t] + red1[2 * t + 1]);
    __syncthreads();
    if (t < 48) { red1[t] = cv; red2[t] = cv * cv; }
    else if (t < 64) { red1[t] = 0.f; red2[t] = 0.f; }
    __syncthreads();
    for (int st = 32; st > 0; st >>= 1) {
        if (t < st) { red1[t] += red1[t + st]; red2[t] += red2[t + st]; }
        __syncthreads();
    }
    if (t == 0) {
        float mu = red1[0] * (1.0f / 48.0f);
        float var = red2[0] * (1.0f / 48.0f) - mu * mu;
        stat[0] = mu; stat[1] = rsqrtf(var + 1e-5f);
    }
    __syncthreads();
    if (t < 48) c2[t] = (cv - stat[0]) * stat[1] * ln2g[t] + ln2b[t];
    __syncthreads();
    if (t < 96) {
        float acc = b7[t];
        const float* wr = W7 + t * 48;
#pragma unroll
        for (int j = 0; j < 48; ++j) acc += c2[j] * wr[j];
        u3l[t] = acc;
    }
    __syncthreads();
    if (t < 9) {
        int k = (t < 5) ? t : t - 4;
        const float* bas = (t < 5) ? cosb[k] : sinb[k];
        float acc = 0.f;
#pragma unroll 4
        for (int m = 0; m < 96; ++m) acc += u3l[m] * bas[m];
        coef[t] = acc;
    }
    __syncthreads();
    if (t < 96) {
        float rec = coef[0];
#pragma unroll
        for (int k = 1; k <= 4; ++k)
            rec += 2.0f * (coef[k] * cosb[k][t] + coef[4 + k] * sinb[k][t]);
        u2out[(size_t)n * 96 + t] = u3l[t] + rec * (1.0f / 96.0f);
    }
}

// ---------------------------------------------------------------- k_conv
__global__ void k_conv(const float* __restrict__ u2, const float* __restrict__ tw,
                       const float* __restrict__ tb, float* __restrict__ u4) {
    int b = blockIdx.x, xq = blockIdx.y, t = threadIdx.x;
    int x0 = xq * 24;
    __shared__ float ub[32][26];
    __shared__ float twl[3072];
    for (int i = t; i < 832; i += 256) {
        int ic = i / 26, xx = i % 26;
        int gx = x0 + xx - 1;
        ub[ic][xx] = (gx >= 0 && gx < 96) ? u2[((size_t)b * 32 + ic) * 96 + gx] : 0.f;
    }
    for (int i = t; i < 3072; i += 256) twl[i] = tw[i];
    __syncthreads();
    for (int i = t; i < 768; i += 256) {
        int oc = i / 24, xx = i % 24;
        float acc = tb[oc];
#pragma unroll 8
        for (int ic = 0; ic < 32; ++ic) {
            const float* wv = twl + (oc * 32 + ic) * 3;
            acc += ub[ic][xx] * wv[0] + ub[ic][xx + 1] * wv[1] + ub[ic][xx + 2] * wv[2];
        }
        u4[((size_t)b * 32 + oc) * 96 + x0 + xx] = ub[oc][xx + 1] + geluf(acc);
    }
}

// ---------------------------------------------------------------- k_out
__global__ void k_out(const float* __restrict__ sxf, const float* __restrict__ u4,
                      const float* __restrict__ W8, const float* __restrict__ b8,
                      float* __restrict__ out) {
    int b = blockIdx.x, oq = blockIdx.y, t = threadIdx.x;
    __shared__ float ld[32][193];
    for (int i = t; i < 32 * 96; i += 256) {
        int c = i / 96, j = i % 96;
        ld[c][j]      = sxf[((size_t)(b * 32 + c)) * 96 + j];
        ld[c][96 + j] = u4[((size_t)(b * 32 + c)) * 96 + j];
    }
    __syncthreads();
    for (int i = t; i < 24 * 32; i += 256) {
        int o = oq * 24 + (i >> 5), c = i & 31;
        float acc = b8[o];
        const float* wr = W8 + o * 192;
#pragma unroll 4
        for (int j = 0; j < 192; ++j) acc += ld[c][j] * wr[j];
        out[((size_t)b * 96 + o) * 32 + c] = acc;
    }
}

// ---------------------------------------------------------------- launch
extern "C" void kernel_launch(void* const* d_in, const int* in_sizes, int n_in,
                              void* d_out, int out_size, void* d_ws, size_t ws_size,
                              hipStream_t stream) {
    const float* s    = (const float*)d_in[0];
    const float* t    = (const float*)d_in[1];
    const int*   cyc  = (const int*)d_in[2];
    const float* rw1  = (const float*)d_in[3];
    const float* rb1  = (const float*)d_in[4];
    const float* rw2  = (const float*)d_in[5];
    const float* rb2  = (const float*)d_in[6];
    const float* A0   = (const float*)d_in[7];
    const float* A1   = (const float*)d_in[8];
    const float* A2   = (const float*)d_in[9];
    const float* P0   = (const float*)d_in[10];
    const float* P1   = (const float*)d_in[11];
    const float* P2   = (const float*)d_in[12];
    const float* Wqkv = (const float*)d_in[13];
    const float* bqkv = (const float*)d_in[14];
    const float* Wo   = (const float*)d_in[15];
    const float* bo   = (const float*)d_in[16];
    const float* alpha= (const float*)d_in[17];
    const float* bn_g = (const float*)d_in[18];
    const float* bn_b = (const float*)d_in[19];
    const float* W3   = (const float*)d_in[20];
    const float* b3   = (const float*)d_in[21];
    const float* W4   = (const float*)d_in[22];
    const float* b4   = (const float*)d_in[23];
    const float* W5   = (const float*)d_in[24];
    const float* b5   = (const float*)d_in[25];
    const float* W6   = (const float*)d_in[26];
    const float* b6   = (const float*)d_in[27];
    const float* W7   = (const float*)d_in[28];
    const float* b7   = (const float*)d_in[29];
    const float* W8   = (const float*)d_in[30];
    const float* b8   = (const float*)d_in[31];
    const float* ln1g = (const float*)d_in[32];
    const float* ln1b = (const float*)d_in[33];
    const float* ln2g = (const float*)d_in[34];
    const float* ln2b = (const float*)d_in[35];
    const float* tew  = (const float*)d_in[36];
    const float* teb  = (const float*)d_in[37];

    const size_t need4 = (size_t)(4864 + 2097152 + 4 * (98304 + 3145728)) * 4;
    int NS = (ws_size >= need4) ? 4 : 2;
    int klen = I_ / NS;

    float* ws     = (float*)d_ws;
    float* wp     = ws;                         // 192
    float* phis   = ws + 192;                   // 4096
    float* bnpart = ws + 4288;                  // 512
    float* srow   = ws + 4864;                  // 1048576
    float* trow   = srow + 1048576;             // 1048576
    float* R      = trow + 1048576;             // overlay region
    float* pd  = R;                             // 98304*NS
    float* pcs = R + (size_t)98304 * NS;        // 3145728*NS
    float* sx  = R;                             // 2097152
    float* g3  = R + 2097152;                   // 393216
    float* sxf = R + 2490368;                   // 196608
    float* u1  = R + 2686976;                   // 786432
    float* u2f = R + 3473408;                   // 196608
    float* u4f = R + 3670016;                   // 196608
    float* out = (float*)d_out;

    k_headphi<<<64, 256, 0, stream>>>(s, rw1, rb1, rw2, rb2, P0, P1, P2, cyc, wp, phis);
    k_attn<<<dim3(2 * NS, 3, 64), 256, 0, stream>>>(s, cyc, A0, A1, A2, P0, P1, P2, pd, pcs, NS, klen);
    k_combine<<<dim3(64, 16), 256, 0, stream>>>(s, t, pd, pcs, wp, srow, trow, NS);
    k_patch<<<2048, 256, 0, stream>>>(srow, phis, Wqkv, bqkv, Wo, bo, alpha, sx);
    k_bn_stats<<<dim3(64, 4), 256, 0, stream>>>(sx, bnpart);
    k_bn_apply<<<2048, 256, 0, stream>>>(sx, bnpart, bn_g, bn_b);
    k_gemm32<1><<<dim3(64, 6), 128, 0, stream>>>(sx, W3, b3, g3, 2048, 192, 1024);
    k_rowmlp4<<<2048, 128, 0, stream>>>(g3, W4, b4, sxf);
    k_gemm32<0><<<dim3(64, 12), 128, 0, stream>>>(trow, W5, b5, u1, 2048, 384, 512);
    k_u<<<2048, 192, 0, stream>>>(u1, ln1g, ln1b, W6, b6, ln2g, ln2b, W7, b7, u2f);
    k_conv<<<dim3(64, 4), 256, 0, stream>>>(u2f, tew, teb, u4f);
    k_out<<<dim3(64, 4), 256, 0, stream>>>(sxf, u4f, W8, b8, out);
}

// Round 5
// 377.995 us; speedup vs baseline: 1.2467x; 1.2467x over previous
//
#include <hip/hip_runtime.h>
#include <math.h>

#define B_    64
#define I_    512
#define C_    32
#define PRED_ 96
#define PL_   16
#define ST_   8
#define NH_   8
#define PN_   64
#define N_    2048

typedef short bf16x8 __attribute__((ext_vector_type(8)));
typedef float f32x4 __attribute__((ext_vector_type(4)));
typedef bf16x8 __attribute__((may_alias)) bf16x8_a;
typedef uint2 __attribute__((may_alias)) uint2_a;
typedef uint4 __attribute__((may_alias)) uint4_a;

__device__ __forceinline__ float geluf(float x) {
    return 0.5f * x * (1.0f + erff(x * 0.70710678118654752f));
}
__device__ __forceinline__ float softplusf(float x) {
    return fmaxf(x, 0.0f) + log1pf(__expf(-fabsf(x)));
}
__device__ __forceinline__ unsigned short f2bf(float x) {
    union { float f; unsigned int u; } v; v.f = x;
    unsigned int r = v.u + 0x7fffu + ((v.u >> 16) & 1u);
    return (unsigned short)(r >> 16);
}

// ---------------------------------------------------------------- k_headphi
__global__ void k_headphi(const float* __restrict__ s, const float* __restrict__ rw1,
                          const float* __restrict__ rb1, const float* __restrict__ rw2,
                          const float* __restrict__ rb2,
                          const float* __restrict__ P0, const float* __restrict__ P1,
                          const float* __restrict__ P2, const int* __restrict__ cyc,
                          float* __restrict__ wp, float* __restrict__ phis) {
    int b = blockIdx.x, t = threadIdx.x;
    __shared__ float part[8][32];
    __shared__ float smean[32];
    __shared__ float h[16];
    __shared__ float wpl[3];
    __shared__ float pm[I_];
    int c = t & 31, chunk = t >> 5;
    float acc = 0.f;
    for (int l = chunk * 64; l < chunk * 64 + 64; ++l)
        acc += s[((size_t)b * I_ + l) * C_ + c];
    part[chunk][c] = acc;
    __syncthreads();
    if (t < 32) {
        float v = 0.f;
#pragma unroll
        for (int i = 0; i < 8; ++i) v += part[i][t];
        smean[t] = v * (1.0f / I_);
    }
    __syncthreads();
    if (t < 16) {
        float a = rb1[t];
#pragma unroll
        for (int c2 = 0; c2 < 32; ++c2) a += smean[c2] * rw1[t * 32 + c2];
        h[t] = geluf(a);
    }
    __syncthreads();
    if (t == 0) {
        float lg[3], mx = -1e30f;
        for (int k = 0; k < 3; ++k) {
            float a = rb2[k];
            for (int j = 0; j < 16; ++j) a += h[j] * rw2[k * 16 + j];
            lg[k] = a; mx = fmaxf(mx, a);
        }
        float d = 0.f;
        for (int k = 0; k < 3; ++k) { lg[k] = __expf(lg[k] - mx); d += lg[k]; }
        float inv = 1.f / d;
        for (int k = 0; k < 3; ++k) { wpl[k] = lg[k] * inv; wp[b * 3 + k] = lg[k] * inv; }
    }
    __syncthreads();
    float p0 = wpl[0], p1 = wpl[1], p2 = wpl[2];
    int cy = cyc[b];
    for (int l = t; l < I_; l += 256) {
        float acc2 = 0.f;
        {
            int idx = (cy + l) % 24;
            const float4* r = (const float4*)(P0 + idx * 32);
            float s4 = 0.f;
#pragma unroll
            for (int i = 0; i < 8; ++i) { float4 v = r[i]; s4 += v.x + v.y + v.z + v.w; }
            acc2 += p0 * s4;
        }
        {
            int idx = (cy + l) % 168;
            const float4* r = (const float4*)(P1 + idx * 32);
            float s4 = 0.f;
#pragma unroll
            for (int i = 0; i < 8; ++i) { float4 v = r[i]; s4 += v.x + v.y + v.z + v.w; }
            acc2 += p1 * s4;
        }
        {
            int idx = (cy + l) % 336;
            const float4* r = (const float4*)(P2 + idx * 32);
            float s4 = 0.f;
#pragma unroll
            for (int i = 0; i < 8; ++i) { float4 v = r[i]; s4 += v.x + v.y + v.z + v.w; }
            acc2 += p2 * s4;
        }
        pm[l] = acc2 * (1.0f / 32.0f);
    }
    __syncthreads();
    if (t < PN_) {
        float sum = 0.f;
#pragma unroll
        for (int j = 0; j < 16; ++j) {
            int l = t * ST_ + j; if (l > 511) l = 511;
            sum += pm[l];
        }
        phis[b * PN_ + t] = sum * (1.0f / 16.0f);
    }
}

// ---------------------------------------------------------------- k_attn_mfma
// One block per (k3, b): full softmax via bf16 MFMA.
// Swapped QK^T: S-tile D[key][q] = mfma(A=s_keys, B=Qr); P relayout through
// padded LDS (Pt); PV: D[q][c] = mfma(A=Pt, B=sT). Output wp/d-normalized.
__global__ void __launch_bounds__(512) k_attn_mfma(
        const float* __restrict__ s, const int* __restrict__ cyc,
        const float* __restrict__ A0, const float* __restrict__ A1, const float* __restrict__ A2,
        const float* __restrict__ P0, const float* __restrict__ P1, const float* __restrict__ P2,
        const float* __restrict__ wp, float* __restrict__ pcs) {
    int k3 = blockIdx.x, b = blockIdx.y;
    int t = threadIdx.x;
    int wid = t >> 6, lane = t & 63;
    int l15 = lane & 15, lg = lane >> 4;

    __shared__ unsigned short s_lds[512][40];   // bf16 bits, row-major [key][c], pad 40
    __shared__ unsigned short sT[32][520];      // bf16 bits, [c][key], pad 520
    __shared__ unsigned short Pt[8][64][40];    // per-wave P tiles [q][key-chunk], pad 40

    // ---- stage s[b] into both layouts (one row per thread) ----
    {
        int row = t;
        const float4* src = (const float4*)(s + ((size_t)b * I_ + row) * C_);
        unsigned short bv[32];
#pragma unroll
        for (int i = 0; i < 8; ++i) {
            float4 v = src[i];
            bv[4 * i + 0] = f2bf(v.x); bv[4 * i + 1] = f2bf(v.y);
            bv[4 * i + 2] = f2bf(v.z); bv[4 * i + 3] = f2bf(v.w);
        }
#pragma unroll
        for (int i = 0; i < 4; ++i) {
            uint4 pk;
            pk.x = (unsigned)bv[8 * i + 0] | ((unsigned)bv[8 * i + 1] << 16);
            pk.y = (unsigned)bv[8 * i + 2] | ((unsigned)bv[8 * i + 3] << 16);
            pk.z = (unsigned)bv[8 * i + 4] | ((unsigned)bv[8 * i + 5] << 16);
            pk.w = (unsigned)bv[8 * i + 6] | ((unsigned)bv[8 * i + 7] << 16);
            *((uint4_a*)&s_lds[row][8 * i]) = pk;
        }
#pragma unroll
        for (int cc = 0; cc < 32; ++cc) sT[cc][row] = bv[cc];
    }

    // ---- Qr fragments in registers (B-operand of S): lane q=l15, ch=8*lg+j ----
    const float* Atab; const float* Ptab; int Wk;
    if (k3 == 0)      { Atab = A0; Ptab = P0; Wk = 24;  }
    else if (k3 == 1) { Atab = A1; Ptab = P1; Wk = 168; }
    else              { Atab = A2; Ptab = P2; Wk = 336; }
    float wpv = wp[b * 3 + k3];
    int cy = cyc[b];
    bf16x8 qrf[4];
#pragma unroll
    for (int qt = 0; qt < 4; ++qt) {
        int q = wid * 64 + qt * 16 + l15;
        int idx = (cy + q) % Wk;
        const float4* Ar = (const float4*)(Atab + idx * 32 + lg * 8);
        const float4* Pr = (const float4*)(Ptab + idx * 32 + lg * 8);
        float4 a0 = Ar[0], a1 = Ar[1], p0 = Pr[0], p1 = Pr[1];
        float qv[8];
        qv[0] = softplusf(a0.x) * __cosf(p0.x);
        qv[1] = softplusf(a0.y) * __cosf(p0.y);
        qv[2] = softplusf(a0.z) * __cosf(p0.z);
        qv[3] = softplusf(a0.w) * __cosf(p0.w);
        qv[4] = softplusf(a1.x) * __cosf(p1.x);
        qv[5] = softplusf(a1.y) * __cosf(p1.y);
        qv[6] = softplusf(a1.z) * __cosf(p1.z);
        qv[7] = softplusf(a1.w) * __cosf(p1.w);
        bf16x8 f;
#pragma unroll
        for (int j = 0; j < 8; ++j) f[j] = (short)f2bf(qv[j]);
        qrf[qt] = f;
    }
    __syncthreads();

    // ---- main loop over 16 key-chunks of 32 ----
    const float rs = 0.17677669529663687f;  // 1/sqrt(32)
    f32x4 acc[4][2];
#pragma unroll
    for (int qt = 0; qt < 4; ++qt)
#pragma unroll
        for (int ct = 0; ct < 2; ++ct) acc[qt][ct] = (f32x4){0.f, 0.f, 0.f, 0.f};
    float dacc[4] = {0.f, 0.f, 0.f, 0.f};

    for (int kc = 0; kc < 16; ++kc) {
        int key0 = kc * 32;
        bf16x8 a0 = *((const bf16x8_a*)&s_lds[key0 + l15][lg * 8]);
        bf16x8 a1 = *((const bf16x8_a*)&s_lds[key0 + 16 + l15][lg * 8]);
        f32x4 stv[4][2];
#pragma unroll
        for (int qt = 0; qt < 4; ++qt) {
            stv[qt][0] = __builtin_amdgcn_mfma_f32_16x16x32_bf16(a0, qrf[qt], (f32x4){0.f,0.f,0.f,0.f}, 0, 0, 0);
            stv[qt][1] = __builtin_amdgcn_mfma_f32_16x16x32_bf16(a1, qrf[qt], (f32x4){0.f,0.f,0.f,0.f}, 0, 0, 0);
        }
#pragma unroll
        for (int qt = 0; qt < 4; ++qt) {
#pragma unroll
            for (int h = 0; h < 2; ++h) {
                unsigned short pb[4];
                float ds = 0.f;
#pragma unroll
                for (int r = 0; r < 4; ++r) {
                    float e = __expf(stv[qt][h][r] * rs);
                    unsigned short ub = f2bf(e);
                    pb[r] = ub;
                    union { unsigned int u; float f; } bb; bb.u = ((unsigned int)ub) << 16;
                    ds += bb.f;   // d consistent with quantized P
                }
                dacc[qt] += ds;
                uint2 w2;
                w2.x = (unsigned)pb[0] | ((unsigned)pb[1] << 16);
                w2.y = (unsigned)pb[2] | ((unsigned)pb[3] << 16);
                *((uint2_a*)&Pt[wid][qt * 16 + l15][h * 16 + lg * 4]) = w2;
            }
        }
        bf16x8 b0 = *((const bf16x8_a*)&sT[l15][key0 + lg * 8]);
        bf16x8 b1 = *((const bf16x8_a*)&sT[16 + l15][key0 + lg * 8]);
#pragma unroll
        for (int qt = 0; qt < 4; ++qt) {
            bf16x8 pa = *((const bf16x8_a*)&Pt[wid][qt * 16 + l15][lg * 8]);
            acc[qt][0] = __builtin_amdgcn_mfma_f32_16x16x32_bf16(pa, b0, acc[qt][0], 0, 0, 0);
            acc[qt][1] = __builtin_amdgcn_mfma_f32_16x16x32_bf16(pa, b1, acc[qt][1], 0, 0, 0);
        }
    }

    // ---- epilogue: reduce d, normalize, store ----
#pragma unroll
    for (int qt = 0; qt < 4; ++qt) {
        float dq = dacc[qt];
        dq += __shfl_xor(dq, 16);
        dq += __shfl_xor(dq, 32);           // lane holds d[q = l15]
        float invd[4];
#pragma unroll
        for (int r = 0; r < 4; ++r) {
            float dr = __shfl(dq, 4 * lg + r);   // d for row q = 4*lg + r
            invd[r] = wpv / dr;
        }
        int qbase = wid * 64 + qt * 16 + 4 * lg;
#pragma unroll
        for (int ct = 0; ct < 2; ++ct) {
            int c = ct * 16 + l15;
            float4 o;
            o.x = acc[qt][ct][0] * invd[0];
            o.y = acc[qt][ct][1] * invd[1];
            o.z = acc[qt][ct][2] * invd[2];
            o.w = acc[qt][ct][3] * invd[3];
            *(float4*)(pcs + (((size_t)k3 * B_ + b) * C_ + c) * I_ + qbase) = o;
        }
    }
}

// ---------------------------------------------------------------- k_combine
// sum 3 normalized scale outputs + s, transpose (b,l,c)->(n,l); also transpose t.
__global__ void k_combine(const float* __restrict__ s, const float* __restrict__ t,
                          const float* __restrict__ pcs,
                          float* __restrict__ srow, float* __restrict__ trow) {
    int b = blockIdx.x, l0 = blockIdx.y * 32;
    int tt_ = threadIdx.x;
    __shared__ float st[32][33], tl[32][33];
#pragma unroll
    for (int r = 0; r < 4; ++r) {
        int lin = r * 256 + tt_;
        int lq = lin >> 5, c = lin & 31;
        st[lq][c] = s[((size_t)b * I_ + l0 + lq) * C_ + c];
        tl[lq][c] = t[((size_t)b * I_ + l0 + lq) * C_ + c];
    }
    __syncthreads();
    const size_t CH = (size_t)B_ * C_ * I_;
#pragma unroll
    for (int r = 0; r < 4; ++r) {
        int lin = r * 256 + tt_;
        int co = lin >> 5, lo = lin & 31;
        size_t pi = ((size_t)b * C_ + co) * I_ + l0 + lo;
        float sum = pcs[pi] + pcs[CH + pi] + pcs[2 * CH + pi];
        size_t oi = ((size_t)(b * C_ + co)) * I_ + l0 + lo;
        srow[oi] = st[lo][co] + sum;
        trow[oi] = tl[lo][co];
    }
}

// ---------------------------------------------------------------- k_patch
__global__ void __launch_bounds__(256) k_patch(
        const float* __restrict__ srow, const float* __restrict__ phis,
        const float* __restrict__ Wqkv, const float* __restrict__ bqkv,
        const float* __restrict__ Wo, const float* __restrict__ bo,
        const float* __restrict__ alpha_p, float* __restrict__ sx) {
    int n = blockIdx.x, t = threadIdx.x;
    int p = t & 63, w = t >> 6;
    int b = n >> 5;
    __shared__ float spl[64][17];
    __shared__ float ql[64][17], kl[64][17], vl[64][17];
    __shared__ float blds[64][65];
    __shared__ float phil[64];
    __shared__ float wq[48][16];
    __shared__ float wo[16][16];
    __shared__ float o2l[64][17];
    float alpha = alpha_p[0];
    for (int i = t; i < 768; i += 256) wq[i >> 4][i & 15] = Wqkv[i];
    if (t < 256) wo[t >> 4][t & 15] = Wo[t];
    if (t < 64) phil[t] = phis[b * PN_ + t];
    const float* srn = srow + (size_t)n * I_;
#pragma unroll
    for (int jj = 0; jj < 4; ++jj) {
        int j = w * 4 + jj;
        int l = p * ST_ + j; if (l > 511) l = 511;
        spl[p][j] = srn[l];
    }
    __syncthreads();
#pragma unroll
    for (int oo = 0; oo < 12; ++oo) {
        int o = w * 12 + oo;
        float a = bqkv[o];
#pragma unroll
        for (int i2 = 0; i2 < 16; ++i2) a += spl[p][i2] * wq[o][i2];
        if (o < 16) ql[p][o] = a;
        else if (o < 32) kl[p][o - 16] = a;
        else vl[p][o - 32] = a;
    }
    float phit = phil[p];
#pragma unroll
    for (int jj = 0; jj < 16; ++jj) {
        int ss = w * 16 + jj;
        blds[p][ss] = alpha * __cosf(phit - phil[ss]);
    }
    __syncthreads();
    const float rs2 = 0.70710678118654752f;
#pragma unroll
    for (int hh = 0; hh < 2; ++hh) {
        int h = 2 * w + hh;
        float q0 = ql[p][2 * h], q1 = ql[p][2 * h + 1];
        float mh = -1e30f;
        for (int ss = 0; ss < 64; ++ss) {
            float sc = (q0 * kl[ss][2 * h] + q1 * kl[ss][2 * h + 1]) * rs2 + blds[p][ss];
            mh = fmaxf(mh, sc);
        }
        float dh = 0.f, o0 = 0.f, o1 = 0.f;
        for (int ss = 0; ss < 64; ++ss) {
            float sc = (q0 * kl[ss][2 * h] + q1 * kl[ss][2 * h + 1]) * rs2 + blds[p][ss];
            float wgt = __expf(sc - mh);
            dh += wgt; o0 += wgt * vl[ss][2 * h]; o1 += wgt * vl[ss][2 * h + 1];
        }
        float inv = 1.f / dh;
        o2l[p][2 * h] = o0 * inv; o2l[p][2 * h + 1] = o1 * inv;
    }
    __syncthreads();
    float* sxr = sx + ((size_t)n * PN_ + p) * PL_;
#pragma unroll
    for (int ii = 0; ii < 4; ++ii) {
        int i2 = w * 4 + ii;
        float a = bo[i2];
#pragma unroll
        for (int j = 0; j < 16; ++j) a += o2l[p][j] * wo[i2][j];
        sxr[i2] = geluf(spl[p][i2] + a);
    }
}

// ---------------------------------------------------------------- k_bn_stats
__global__ void k_bn_stats(const float* __restrict__ sx, float* __restrict__ bnpart) {
    int pn = blockIdx.x, chunk = blockIdx.y, t = threadIdx.x;
    __shared__ float r1[256], r2[256];
    int j4 = t & 3, nb = t >> 2;
    float s1 = 0.f, s2 = 0.f;
    for (int i = 0; i < 8; ++i) {
        int n = chunk * 512 + nb + i * 64;
        float4 v = *(const float4*)(sx + ((size_t)n * PN_ + pn) * PL_ + j4 * 4);
        s1 += v.x + v.y + v.z + v.w;
        s2 += v.x * v.x + v.y * v.y + v.z * v.z + v.w * v.w;
    }
    r1[t] = s1; r2[t] = s2;
    __syncthreads();
    for (int st = 128; st > 0; st >>= 1) {
        if (t < st) { r1[t] += r1[t + st]; r2[t] += r2[t + st]; }
        __syncthreads();
    }
    if (t == 0) {
        bnpart[(pn * 4 + chunk) * 2 + 0] = r1[0];
        bnpart[(pn * 4 + chunk) * 2 + 1] = r2[0];
    }
}

// ---------------------------------------------------------------- k_bn_apply
__global__ void k_bn_apply(float* __restrict__ sx, const float* __restrict__ bnpart,
                           const float* __restrict__ g, const float* __restrict__ bb) {
    int g4 = blockIdx.x * 256 + threadIdx.x;
    int pn = (g4 >> 2) & 63;
    float s1 = 0.f, s2 = 0.f;
#pragma unroll
    for (int ch = 0; ch < 4; ++ch) {
        s1 += bnpart[(pn * 4 + ch) * 2 + 0];
        s2 += bnpart[(pn * 4 + ch) * 2 + 1];
    }
    const float inv = 1.0f / (N_ * PL_);
    float mu = s1 * inv;
    float var = s2 * inv - mu * mu;
    float rstd = rsqrtf(var + 1e-5f);
    float gg = g[pn], bbv = bb[pn];
    float4* p = (float4*)sx + g4;
    float4 v = *p;
    v.x = (v.x - mu) * rstd * gg + bbv;
    v.y = (v.y - mu) * rstd * gg + bbv;
    v.z = (v.z - mu) * rstd * gg + bbv;
    v.w = (v.w - mu) * rstd * gg + bbv;
    *p = v;
}

// ---------------------------------------------------------------- k_gemm32
template <int ACT>
__global__ void __launch_bounds__(128) k_gemm32(const float* __restrict__ A,
                                                const float* __restrict__ W,
                                                const float* __restrict__ bias,
                                                float* __restrict__ Cout,
                                                int M, int Nn, int K) {
    __shared__ float at[32][36];
    __shared__ float wt[32][36];
    int bm = blockIdx.x * 32, bn = blockIdx.y * 32;
    int t = threadIdx.x;
    int lr = t >> 2, lk = (t & 3) * 8;
    int tm = (t & 15) * 2, tn = (t >> 4) * 4;
    float acc[2][4] = {};
    for (int k0 = 0; k0 < K; k0 += 32) {
        float4 a0 = *(const float4*)(A + (size_t)(bm + lr) * K + k0 + lk);
        float4 a1 = *(const float4*)(A + (size_t)(bm + lr) * K + k0 + lk + 4);
        float4 w0 = *(const float4*)(W + (size_t)(bn + lr) * K + k0 + lk);
        float4 w1 = *(const float4*)(W + (size_t)(bn + lr) * K + k0 + lk + 4);
        __syncthreads();
        at[lk + 0][lr] = a0.x; at[lk + 1][lr] = a0.y; at[lk + 2][lr] = a0.z; at[lk + 3][lr] = a0.w;
        at[lk + 4][lr] = a1.x; at[lk + 5][lr] = a1.y; at[lk + 6][lr] = a1.z; at[lk + 7][lr] = a1.w;
        wt[lk + 0][lr] = w0.x; wt[lk + 1][lr] = w0.y; wt[lk + 2][lr] = w0.z; wt[lk + 3][lr] = w0.w;
        wt[lk + 4][lr] = w1.x; wt[lk + 5][lr] = w1.y; wt[lk + 6][lr] = w1.z; wt[lk + 7][lr] = w1.w;
        __syncthreads();
#pragma unroll
        for (int kk = 0; kk < 32; ++kk) {
            float2 a2 = *(const float2*)&at[kk][tm];
            float4 w4 = *(const float4*)&wt[kk][tn];
            acc[0][0] += a2.x * w4.x; acc[0][1] += a2.x * w4.y;
            acc[0][2] += a2.x * w4.z; acc[0][3] += a2.x * w4.w;
            acc[1][0] += a2.y * w4.x; acc[1][1] += a2.y * w4.y;
            acc[1][2] += a2.y * w4.z; acc[1][3] += a2.y * w4.w;
        }
    }
#pragma unroll
    for (int i = 0; i < 2; ++i) {
#pragma unroll
        for (int j = 0; j < 4; ++j) {
            float v = acc[i][j] + bias[bn + tn + j];
            if (ACT) v = geluf(v);
            Cout[(size_t)(bm + tm + i) * Nn + bn + tn + j] = v;
        }
    }
}

// ---------------------------------------------------------------- k_rowmlp4
__global__ void k_rowmlp4(const float* __restrict__ g3, const float* __restrict__ W4,
                          const float* __restrict__ b4, float* __restrict__ sxf) {
    int n = blockIdx.x, t = threadIdx.x;  // 128 threads
    __shared__ float row[192];
    for (int j = t; j < 192; j += 128) row[j] = g3[(size_t)n * 192 + j];
    __syncthreads();
    if (t < 96) {
        float a = b4[t];
        const float* wr = W4 + t * 192;
#pragma unroll 4
        for (int j = 0; j < 192; ++j) a += row[j] * wr[j];
        sxf[(size_t)n * 96 + t] = a;
    }
}

// ---------------------------------------------------------------- k_u (+ fused low-pass)
__global__ void k_u(const float* __restrict__ u1, const float* __restrict__ ln1g,
                    const float* __restrict__ ln1b, const float* __restrict__ W6,
                    const float* __restrict__ b6, const float* __restrict__ ln2g,
                    const float* __restrict__ ln2b, const float* __restrict__ W7,
                    const float* __restrict__ b7, float* __restrict__ u2out) {
    int n = blockIdx.x, t = threadIdx.x;  // 192 threads
    __shared__ float a[192];
    __shared__ float red1[256], red2[256];
    __shared__ float c2[48];
    __shared__ float stat[2];
    __shared__ float u3l[96];
    __shared__ float cosb[5][96], sinb[5][96];
    __shared__ float coef[9];
    if (t < 96) {
#pragma unroll
        for (int k = 0; k < 5; ++k) {
            float sv, cv2;
            __sincosf(6.283185307179586f * (float)(k * t) / 96.0f, &sv, &cv2);
            cosb[k][t] = cv2; sinb[k][t] = sv;
        }
    }
    const float* ur = u1 + (size_t)n * 384;
    float av = 0.5f * (ur[2 * t] + ur[2 * t + 1]);
    red1[t] = av; red2[t] = av * av;
    if (t < 64) { red1[192 + t] = 0.f; red2[192 + t] = 0.f; }
    __syncthreads();
    for (int st = 128; st > 0; st >>= 1) {
        if (t < st) { red1[t] += red1[t + st]; red2[t] += red2[t + st]; }
        __syncthreads();
    }
    if (t == 0) {
        float mu = red1[0] * (1.0f / 192.0f);
        float var = red2[0] * (1.0f / 192.0f) - mu * mu;
        stat[0] = mu; stat[1] = rsqrtf(var + 1e-5f);
    }
    __syncthreads();
    a[t] = (av - stat[0]) * stat[1] * ln1g[t] + ln1b[t];
    __syncthreads();
    float bv = 0.f;
    if (t < 96) {
        bv = b6[t];
        const float* wr = W6 + t * 192;
#pragma unroll 4
        for (int j = 0; j < 192; ++j) bv += a[j] * wr[j];
    }
    __syncthreads();
    if (t < 96) red1[t] = bv;
    __syncthreads();
    float cv = 0.f;
    if (t < 48) cv = 0.5f * (red1[2 * t] + red1[2 * t + 1]);
    __syncthreads();
    if (t < 48) { red1[t] = cv; red2[t] = cv * cv; }
    else if (t < 64) { red1[t] = 0.f; red2[t] = 0.f; }
    __syncthreads();
    for (int st = 32; st > 0; st >>= 1) {
        if (t < st) { red1[t] += red1[t + st]; red2[t] += red2[t + st]; }
        __syncthreads();
    }
    if (t == 0) {
        float mu = red1[0] * (1.0f / 48.0f);
        float var = red2[0] * (1.0f / 48.0f) - mu * mu;
        stat[0] = mu; stat[1] = rsqrtf(var + 1e-5f);
    }
    __syncthreads();
    if (t < 48) c2[t] = (cv - stat[0]) * stat[1] * ln2g[t] + ln2b[t];
    __syncthreads();
    if (t < 96) {
        float acc = b7[t];
        const float* wr = W7 + t * 48;
#pragma unroll
        for (int j = 0; j < 48; ++j) acc += c2[j] * wr[j];
        u3l[t] = acc;
    }
    __syncthreads();
    if (t < 9) {
        int k = (t < 5) ? t : t - 4;
        const float* bas = (t < 5) ? cosb[k] : sinb[k];
        float acc = 0.f;
#pragma unroll 4
        for (int m = 0; m < 96; ++m) acc += u3l[m] * bas[m];
        coef[t] = acc;
    }
    __syncthreads();
    if (t < 96) {
        float rec = coef[0];
#pragma unroll
        for (int k = 1; k <= 4; ++k)
            rec += 2.0f * (coef[k] * cosb[k][t] + coef[4 + k] * sinb[k][t]);
        u2out[(size_t)n * 96 + t] = u3l[t] + rec * (1.0f / 96.0f);
    }
}

// ---------------------------------------------------------------- k_conv
__global__ void k_conv(const float* __restrict__ u2, const float* __restrict__ tw,
                       const float* __restrict__ tb, float* __restrict__ u4) {
    int b = blockIdx.x, xq = blockIdx.y, t = threadIdx.x;
    int x0 = xq * 24;
    __shared__ float ub[32][26];
    __shared__ float twl[3072];
    for (int i = t; i < 832; i += 256) {
        int ic = i / 26, xx = i % 26;
        int gx = x0 + xx - 1;
        ub[ic][xx] = (gx >= 0 && gx < 96) ? u2[((size_t)b * 32 + ic) * 96 + gx] : 0.f;
    }
    for (int i = t; i < 3072; i += 256) twl[i] = tw[i];
    __syncthreads();
    for (int i = t; i < 768; i += 256) {
        int oc = i / 24, xx = i % 24;
        float acc = tb[oc];
#pragma unroll 8
        for (int ic = 0; ic < 32; ++ic) {
            const float* wv = twl + (oc * 32 + ic) * 3;
            acc += ub[ic][xx] * wv[0] + ub[ic][xx + 1] * wv[1] + ub[ic][xx + 2] * wv[2];
        }
        u4[((size_t)b * 32 + oc) * 96 + x0 + xx] = ub[oc][xx + 1] + geluf(acc);
    }
}

// ---------------------------------------------------------------- k_out
__global__ void k_out(const float* __restrict__ sxf, const float* __restrict__ u4,
                      const float* __restrict__ W8, const float* __restrict__ b8,
                      float* __restrict__ out) {
    int b = blockIdx.x, oq = blockIdx.y, t = threadIdx.x;
    __shared__ float ld[32][193];
    for (int i = t; i < 32 * 96; i += 256) {
        int c = i / 96, j = i % 96;
        ld[c][j]      = sxf[((size_t)(b * 32 + c)) * 96 + j];
        ld[c][96 + j] = u4[((size_t)(b * 32 + c)) * 96 + j];
    }
    __syncthreads();
    for (int i = t; i < 24 * 32; i += 256) {
        int o = oq * 24 + (i >> 5), c = i & 31;
        float acc = b8[o];
        const float* wr = W8 + o * 192;
#pragma unroll 4
        for (int j = 0; j < 192; ++j) acc += ld[c][j] * wr[j];
        out[((size_t)b * 96 + o) * 32 + c] = acc;
    }
}

// ---------------------------------------------------------------- launch
extern "C" void kernel_launch(void* const* d_in, const int* in_sizes, int n_in,
                              void* d_out, int out_size, void* d_ws, size_t ws_size,
                              hipStream_t stream) {
    const float* s    = (const float*)d_in[0];
    const float* t    = (const float*)d_in[1];
    const int*   cyc  = (const int*)d_in[2];
    const float* rw1  = (const float*)d_in[3];
    const float* rb1  = (const float*)d_in[4];
    const float* rw2  = (const float*)d_in[5];
    const float* rb2  = (const float*)d_in[6];
    const float* A0   = (const float*)d_in[7];
    const float* A1   = (const float*)d_in[8];
    const float* A2   = (const float*)d_in[9];
    const float* P0   = (const float*)d_in[10];
    const float* P1   = (const float*)d_in[11];
    const float* P2   = (const float*)d_in[12];
    const float* Wqkv = (const float*)d_in[13];
    const float* bqkv = (const float*)d_in[14];
    const float* Wo   = (const float*)d_in[15];
    const float* bo   = (const float*)d_in[16];
    const float* alpha= (const float*)d_in[17];
    const float* bn_g = (const float*)d_in[18];
    const float* bn_b = (const float*)d_in[19];
    const float* W3   = (const float*)d_in[20];
    const float* b3   = (const float*)d_in[21];
    const float* W4   = (const float*)d_in[22];
    const float* b4   = (const float*)d_in[23];
    const float* W5   = (const float*)d_in[24];
    const float* b5   = (const float*)d_in[25];
    const float* W6   = (const float*)d_in[26];
    const float* b6   = (const float*)d_in[27];
    const float* W7   = (const float*)d_in[28];
    const float* b7   = (const float*)d_in[29];
    const float* W8   = (const float*)d_in[30];
    const float* b8   = (const float*)d_in[31];
    const float* ln1g = (const float*)d_in[32];
    const float* ln1b = (const float*)d_in[33];
    const float* ln2g = (const float*)d_in[34];
    const float* ln2b = (const float*)d_in[35];
    const float* tew  = (const float*)d_in[36];
    const float* teb  = (const float*)d_in[37];

    float* ws     = (float*)d_ws;
    float* wp     = ws;                         // 192
    float* phis   = ws + 192;                   // 4096
    float* bnpart = ws + 4288;                  // 512
    float* srow   = ws + 4864;                  // 1048576
    float* trow   = srow + 1048576;             // 1048576
    float* R      = trow + 1048576;             // overlay region
    // phase 1 overlay
    float* pcs = R;                             // 3*64*32*512 = 3145728
    // phase 2 overlay
    float* sx  = R;                             // 2097152
    float* g3  = R + 2097152;                   // 393216
    float* sxf = R + 2490368;                   // 196608
    float* u1  = R + 2686976;                   // 786432
    float* u2f = R + 3473408;                   // 196608
    float* u4f = R + 3670016;                   // 196608
    float* out = (float*)d_out;

    k_headphi<<<64, 256, 0, stream>>>(s, rw1, rb1, rw2, rb2, P0, P1, P2, cyc, wp, phis);
    k_attn_mfma<<<dim3(3, 64), 512, 0, stream>>>(s, cyc, A0, A1, A2, P0, P1, P2, wp, pcs);
    k_combine<<<dim3(64, 16), 256, 0, stream>>>(s, t, pcs, srow, trow);
    k_patch<<<2048, 256, 0, stream>>>(srow, phis, Wqkv, bqkv, Wo, bo, alpha, sx);
    k_bn_stats<<<dim3(64, 4), 256, 0, stream>>>(sx, bnpart);
    k_bn_apply<<<2048, 256, 0, stream>>>(sx, bnpart, bn_g, bn_b);
    k_gemm32<1><<<dim3(64, 6), 128, 0, stream>>>(sx, W3, b3, g3, 2048, 192, 1024);
    k_rowmlp4<<<2048, 128, 0, stream>>>(g3, W4, b4, sxf);
    k_gemm32<0><<<dim3(64, 12), 128, 0, stream>>>(trow, W5, b5, u1, 2048, 384, 512);
    k_u<<<2048, 192, 0, stream>>>(u1, ln1g, ln1b, W6, b6, ln2g, ln2b, W7, b7, u2f);
    k_conv<<<dim3(64, 4), 256, 0, stream>>>(u2f, tew, teb, u4f);
    k_out<<<dim3(64, 4), 256, 0, stream>>>(sxf, u4f, W8, b8, out);
}

// Round 6
// 351.563 us; speedup vs baseline: 1.3404x; 1.0752x over previous
//
#include <hip/hip_runtime.h>
#include <math.h>

#define B_    64
#define I_    512
#define C_    32
#define PRED_ 96
#define PL_   16
#define ST_   8
#define NH_   8
#define PN_   64
#define N_    2048

typedef short bf16x8 __attribute__((ext_vector_type(8)));
typedef float f32x4 __attribute__((ext_vector_type(4)));
typedef bf16x8 __attribute__((may_alias)) bf16x8_a;
typedef uint2 __attribute__((may_alias)) uint2_a;
typedef uint4 __attribute__((may_alias)) uint4_a;

__device__ __forceinline__ float geluf(float x) {
    return 0.5f * x * (1.0f + erff(x * 0.70710678118654752f));
}
__device__ __forceinline__ float softplusf(float x) {
    return fmaxf(x, 0.0f) + log1pf(__expf(-fabsf(x)));
}
__device__ __forceinline__ unsigned short f2bf(float x) {
    union { float f; unsigned int u; } v; v.f = x;
    unsigned int r = v.u + 0x7fffu + ((v.u >> 16) & 1u);
    return (unsigned short)(r >> 16);
}

// ---------------------------------------------------------------- k_headphi
__global__ void k_headphi(const float* __restrict__ s, const float* __restrict__ rw1,
                          const float* __restrict__ rb1, const float* __restrict__ rw2,
                          const float* __restrict__ rb2,
                          const float* __restrict__ P0, const float* __restrict__ P1,
                          const float* __restrict__ P2, const int* __restrict__ cyc,
                          float* __restrict__ wp, float* __restrict__ phis) {
    int b = blockIdx.x, t = threadIdx.x;
    __shared__ float part[8][32];
    __shared__ float smean[32];
    __shared__ float h[16];
    __shared__ float wpl[3];
    __shared__ float pm[I_];
    int c = t & 31, chunk = t >> 5;
    float acc = 0.f;
    for (int l = chunk * 64; l < chunk * 64 + 64; ++l)
        acc += s[((size_t)b * I_ + l) * C_ + c];
    part[chunk][c] = acc;
    __syncthreads();
    if (t < 32) {
        float v = 0.f;
#pragma unroll
        for (int i = 0; i < 8; ++i) v += part[i][t];
        smean[t] = v * (1.0f / I_);
    }
    __syncthreads();
    if (t < 16) {
        float a = rb1[t];
#pragma unroll
        for (int c2 = 0; c2 < 32; ++c2) a += smean[c2] * rw1[t * 32 + c2];
        h[t] = geluf(a);
    }
    __syncthreads();
    if (t == 0) {
        float lg[3], mx = -1e30f;
        for (int k = 0; k < 3; ++k) {
            float a = rb2[k];
            for (int j = 0; j < 16; ++j) a += h[j] * rw2[k * 16 + j];
            lg[k] = a; mx = fmaxf(mx, a);
        }
        float d = 0.f;
        for (int k = 0; k < 3; ++k) { lg[k] = __expf(lg[k] - mx); d += lg[k]; }
        float inv = 1.f / d;
        for (int k = 0; k < 3; ++k) { wpl[k] = lg[k] * inv; wp[b * 3 + k] = lg[k] * inv; }
    }
    __syncthreads();
    float p0 = wpl[0], p1 = wpl[1], p2 = wpl[2];
    int cy = cyc[b];
    for (int l = t; l < I_; l += 256) {
        float acc2 = 0.f;
        {
            int idx = (cy + l) % 24;
            const float4* r = (const float4*)(P0 + idx * 32);
            float s4 = 0.f;
#pragma unroll
            for (int i = 0; i < 8; ++i) { float4 v = r[i]; s4 += v.x + v.y + v.z + v.w; }
            acc2 += p0 * s4;
        }
        {
            int idx = (cy + l) % 168;
            const float4* r = (const float4*)(P1 + idx * 32);
            float s4 = 0.f;
#pragma unroll
            for (int i = 0; i < 8; ++i) { float4 v = r[i]; s4 += v.x + v.y + v.z + v.w; }
            acc2 += p1 * s4;
        }
        {
            int idx = (cy + l) % 336;
            const float4* r = (const float4*)(P2 + idx * 32);
            float s4 = 0.f;
#pragma unroll
            for (int i = 0; i < 8; ++i) { float4 v = r[i]; s4 += v.x + v.y + v.z + v.w; }
            acc2 += p2 * s4;
        }
        pm[l] = acc2 * (1.0f / 32.0f);
    }
    __syncthreads();
    if (t < PN_) {
        float sum = 0.f;
#pragma unroll
        for (int j = 0; j < 16; ++j) {
            int l = t * ST_ + j; if (l > 511) l = 511;
            sum += pm[l];
        }
        phis[b * PN_ + t] = sum * (1.0f / 16.0f);
    }
}

// ---------------------------------------------------------------- k_attn_mfma
__global__ void __launch_bounds__(512) k_attn_mfma(
        const float* __restrict__ s, const int* __restrict__ cyc,
        const float* __restrict__ A0, const float* __restrict__ A1, const float* __restrict__ A2,
        const float* __restrict__ P0, const float* __restrict__ P1, const float* __restrict__ P2,
        const float* __restrict__ wp, float* __restrict__ pcs) {
    int k3 = blockIdx.x, b = blockIdx.y;
    int t = threadIdx.x;
    int wid = t >> 6, lane = t & 63;
    int l15 = lane & 15, lg = lane >> 4;

    __shared__ unsigned short s_lds[512][40];
    __shared__ unsigned short sT[32][520];
    __shared__ unsigned short Pt[8][64][40];

    {
        int row = t;
        const float4* src = (const float4*)(s + ((size_t)b * I_ + row) * C_);
        unsigned short bv[32];
#pragma unroll
        for (int i = 0; i < 8; ++i) {
            float4 v = src[i];
            bv[4 * i + 0] = f2bf(v.x); bv[4 * i + 1] = f2bf(v.y);
            bv[4 * i + 2] = f2bf(v.z); bv[4 * i + 3] = f2bf(v.w);
        }
#pragma unroll
        for (int i = 0; i < 4; ++i) {
            uint4 pk;
            pk.x = (unsigned)bv[8 * i + 0] | ((unsigned)bv[8 * i + 1] << 16);
            pk.y = (unsigned)bv[8 * i + 2] | ((unsigned)bv[8 * i + 3] << 16);
            pk.z = (unsigned)bv[8 * i + 4] | ((unsigned)bv[8 * i + 5] << 16);
            pk.w = (unsigned)bv[8 * i + 6] | ((unsigned)bv[8 * i + 7] << 16);
            *((uint4_a*)&s_lds[row][8 * i]) = pk;
        }
#pragma unroll
        for (int cc = 0; cc < 32; ++cc) sT[cc][row] = bv[cc];
    }

    const float* Atab; const float* Ptab; int Wk;
    if (k3 == 0)      { Atab = A0; Ptab = P0; Wk = 24;  }
    else if (k3 == 1) { Atab = A1; Ptab = P1; Wk = 168; }
    else              { Atab = A2; Ptab = P2; Wk = 336; }
    float wpv = wp[b * 3 + k3];
    int cy = cyc[b];
    bf16x8 qrf[4];
#pragma unroll
    for (int qt = 0; qt < 4; ++qt) {
        int q = wid * 64 + qt * 16 + l15;
        int idx = (cy + q) % Wk;
        const float4* Ar = (const float4*)(Atab + idx * 32 + lg * 8);
        const float4* Pr = (const float4*)(Ptab + idx * 32 + lg * 8);
        float4 a0 = Ar[0], a1 = Ar[1], p0 = Pr[0], p1 = Pr[1];
        float qv[8];
        qv[0] = softplusf(a0.x) * __cosf(p0.x);
        qv[1] = softplusf(a0.y) * __cosf(p0.y);
        qv[2] = softplusf(a0.z) * __cosf(p0.z);
        qv[3] = softplusf(a0.w) * __cosf(p0.w);
        qv[4] = softplusf(a1.x) * __cosf(p1.x);
        qv[5] = softplusf(a1.y) * __cosf(p1.y);
        qv[6] = softplusf(a1.z) * __cosf(p1.z);
        qv[7] = softplusf(a1.w) * __cosf(p1.w);
        bf16x8 f;
#pragma unroll
        for (int j = 0; j < 8; ++j) f[j] = (short)f2bf(qv[j]);
        qrf[qt] = f;
    }
    __syncthreads();

    const float rs = 0.17677669529663687f;
    f32x4 acc[4][2];
#pragma unroll
    for (int qt = 0; qt < 4; ++qt)
#pragma unroll
        for (int ct = 0; ct < 2; ++ct) acc[qt][ct] = (f32x4){0.f, 0.f, 0.f, 0.f};
    float dacc[4] = {0.f, 0.f, 0.f, 0.f};

    for (int kc = 0; kc < 16; ++kc) {
        int key0 = kc * 32;
        bf16x8 a0 = *((const bf16x8_a*)&s_lds[key0 + l15][lg * 8]);
        bf16x8 a1 = *((const bf16x8_a*)&s_lds[key0 + 16 + l15][lg * 8]);
        f32x4 stv[4][2];
#pragma unroll
        for (int qt = 0; qt < 4; ++qt) {
            stv[qt][0] = __builtin_amdgcn_mfma_f32_16x16x32_bf16(a0, qrf[qt], (f32x4){0.f,0.f,0.f,0.f}, 0, 0, 0);
            stv[qt][1] = __builtin_amdgcn_mfma_f32_16x16x32_bf16(a1, qrf[qt], (f32x4){0.f,0.f,0.f,0.f}, 0, 0, 0);
        }
#pragma unroll
        for (int qt = 0; qt < 4; ++qt) {
#pragma unroll
            for (int h = 0; h < 2; ++h) {
                unsigned short pb[4];
                float ds = 0.f;
#pragma unroll
                for (int r = 0; r < 4; ++r) {
                    float e = __expf(stv[qt][h][r] * rs);
                    unsigned short ub = f2bf(e);
                    pb[r] = ub;
                    union { unsigned int u; float f; } bb; bb.u = ((unsigned int)ub) << 16;
                    ds += bb.f;
                }
                dacc[qt] += ds;
                uint2 w2;
                w2.x = (unsigned)pb[0] | ((unsigned)pb[1] << 16);
                w2.y = (unsigned)pb[2] | ((unsigned)pb[3] << 16);
                *((uint2_a*)&Pt[wid][qt * 16 + l15][h * 16 + lg * 4]) = w2;
            }
        }
        bf16x8 b0 = *((const bf16x8_a*)&sT[l15][key0 + lg * 8]);
        bf16x8 b1 = *((const bf16x8_a*)&sT[16 + l15][key0 + lg * 8]);
#pragma unroll
        for (int qt = 0; qt < 4; ++qt) {
            bf16x8 pa = *((const bf16x8_a*)&Pt[wid][qt * 16 + l15][lg * 8]);
            acc[qt][0] = __builtin_amdgcn_mfma_f32_16x16x32_bf16(pa, b0, acc[qt][0], 0, 0, 0);
            acc[qt][1] = __builtin_amdgcn_mfma_f32_16x16x32_bf16(pa, b1, acc[qt][1], 0, 0, 0);
        }
    }

#pragma unroll
    for (int qt = 0; qt < 4; ++qt) {
        float dq = dacc[qt];
        dq += __shfl_xor(dq, 16);
        dq += __shfl_xor(dq, 32);
        float invd[4];
#pragma unroll
        for (int r = 0; r < 4; ++r) {
            float dr = __shfl(dq, 4 * lg + r);
            invd[r] = wpv / dr;
        }
        int qbase = wid * 64 + qt * 16 + 4 * lg;
#pragma unroll
        for (int ct = 0; ct < 2; ++ct) {
            int c = ct * 16 + l15;
            float4 o;
            o.x = acc[qt][ct][0] * invd[0];
            o.y = acc[qt][ct][1] * invd[1];
            o.z = acc[qt][ct][2] * invd[2];
            o.w = acc[qt][ct][3] * invd[3];
            *(float4*)(pcs + (((size_t)k3 * B_ + b) * C_ + c) * I_ + qbase) = o;
        }
    }
}

// ---------------------------------------------------------------- k_combine
__global__ void k_combine(const float* __restrict__ s, const float* __restrict__ t,
                          const float* __restrict__ pcs,
                          float* __restrict__ srow, float* __restrict__ trow) {
    int b = blockIdx.x, l0 = blockIdx.y * 32;
    int tt_ = threadIdx.x;
    __shared__ float st[32][33], tl[32][33];
#pragma unroll
    for (int r = 0; r < 4; ++r) {
        int lin = r * 256 + tt_;
        int lq = lin >> 5, c = lin & 31;
        st[lq][c] = s[((size_t)b * I_ + l0 + lq) * C_ + c];
        tl[lq][c] = t[((size_t)b * I_ + l0 + lq) * C_ + c];
    }
    __syncthreads();
    const size_t CH = (size_t)B_ * C_ * I_;
#pragma unroll
    for (int r = 0; r < 4; ++r) {
        int lin = r * 256 + tt_;
        int co = lin >> 5, lo = lin & 31;
        size_t pi = ((size_t)b * C_ + co) * I_ + l0 + lo;
        float sum = pcs[pi] + pcs[CH + pi] + pcs[2 * CH + pi];
        size_t oi = ((size_t)(b * C_ + co)) * I_ + l0 + lo;
        srow[oi] = st[lo][co] + sum;
        trow[oi] = tl[lo][co];
    }
}

// ---------------------------------------------------------------- k_patch (v2)
// cos(a-b) decomposition kills the [64][65] bias tile; single-pass softmax
// (scores bounded ~[-1.3,1.3]: q,k are 0.02-scale projections, bias |cos|<=1).
__global__ void __launch_bounds__(256) k_patch(
        const float* __restrict__ srow, const float* __restrict__ phis,
        const float* __restrict__ Wqkv, const float* __restrict__ bqkv,
        const float* __restrict__ Wo, const float* __restrict__ bo,
        const float* __restrict__ alpha_p, float* __restrict__ sx) {
    int n = blockIdx.x, t = threadIdx.x;
    int p = t & 63, w = t >> 6;
    int b = n >> 5;
    __shared__ float spl[64][17];
    __shared__ float ql[64][17], kl[64][17], vl[64][17];
    __shared__ float cosl[64], sinl[64];
    __shared__ float wq[48][16];
    __shared__ float wo[16][16];
    __shared__ float o2l[64][17];
    float alpha = alpha_p[0];
    for (int i = t; i < 768; i += 256) wq[i >> 4][i & 15] = Wqkv[i];
    if (t < 256) wo[t >> 4][t & 15] = Wo[t];
    if (t < 64) {
        float sv, cv;
        __sincosf(phis[b * PN_ + t], &sv, &cv);
        cosl[t] = cv; sinl[t] = sv;
    }
    const float* srn = srow + (size_t)n * I_;
#pragma unroll
    for (int jj = 0; jj < 4; ++jj) {
        int j = w * 4 + jj;
        int l = p * ST_ + j; if (l > 511) l = 511;
        spl[p][j] = srn[l];
    }
    __syncthreads();
#pragma unroll
    for (int oo = 0; oo < 12; ++oo) {
        int o = w * 12 + oo;
        float a = bqkv[o];
#pragma unroll
        for (int i2 = 0; i2 < 16; ++i2) a += spl[p][i2] * wq[o][i2];
        if (o < 16) ql[p][o] = a;
        else if (o < 32) kl[p][o - 16] = a;
        else vl[p][o - 32] = a;
    }
    __syncthreads();
    const float rs2 = 0.70710678118654752f;
    float cp = alpha * cosl[p], sp_ = alpha * sinl[p];
#pragma unroll
    for (int hh = 0; hh < 2; ++hh) {
        int h = 2 * w + hh;
        float q0 = ql[p][2 * h] * rs2, q1 = ql[p][2 * h + 1] * rs2;
        float dh = 0.f, o0 = 0.f, o1 = 0.f;
        for (int ss = 0; ss < 64; ++ss) {
            float sc = q0 * kl[ss][2 * h] + q1 * kl[ss][2 * h + 1]
                     + cp * cosl[ss] + sp_ * sinl[ss];
            float e = __expf(sc);
            dh += e; o0 += e * vl[ss][2 * h]; o1 += e * vl[ss][2 * h + 1];
        }
        float inv = 1.f / dh;
        o2l[p][2 * h] = o0 * inv; o2l[p][2 * h + 1] = o1 * inv;
    }
    __syncthreads();
    float* sxr = sx + ((size_t)n * PN_ + p) * PL_;
#pragma unroll
    for (int ii = 0; ii < 4; ++ii) {
        int i2 = w * 4 + ii;
        float a = bo[i2];
#pragma unroll
        for (int j = 0; j < 16; ++j) a += o2l[p][j] * wo[i2][j];
        sxr[i2] = geluf(spl[p][i2] + a);
    }
}

// ---------------------------------------------------------------- k_bn_stats
__global__ void k_bn_stats(const float* __restrict__ sx, float* __restrict__ bnpart) {
    int pn = blockIdx.x, chunk = blockIdx.y, t = threadIdx.x;
    __shared__ float r1[256], r2[256];
    int j4 = t & 3, nb = t >> 2;
    float s1 = 0.f, s2 = 0.f;
    for (int i = 0; i < 8; ++i) {
        int n = chunk * 512 + nb + i * 64;
        float4 v = *(const float4*)(sx + ((size_t)n * PN_ + pn) * PL_ + j4 * 4);
        s1 += v.x + v.y + v.z + v.w;
        s2 += v.x * v.x + v.y * v.y + v.z * v.z + v.w * v.w;
    }
    r1[t] = s1; r2[t] = s2;
    __syncthreads();
    for (int st = 128; st > 0; st >>= 1) {
        if (t < st) { r1[t] += r1[t + st]; r2[t] += r2[t + st]; }
        __syncthreads();
    }
    if (t == 0) {
        bnpart[(pn * 4 + chunk) * 2 + 0] = r1[0];
        bnpart[(pn * 4 + chunk) * 2 + 1] = r2[0];
    }
}

// ---------------------------------------------------------------- k_bn_final
// per-pn affine coefficients: y = x*bnmul[pn] + bnadd[pn]
__global__ void k_bn_final(const float* __restrict__ bnpart, const float* __restrict__ g,
                           const float* __restrict__ bb, float* __restrict__ bnmul,
                           float* __restrict__ bnadd) {
    int pn = threadIdx.x;  // 64 threads
    float s1 = 0.f, s2 = 0.f;
#pragma unroll
    for (int ch = 0; ch < 4; ++ch) {
        s1 += bnpart[(pn * 4 + ch) * 2 + 0];
        s2 += bnpart[(pn * 4 + ch) * 2 + 1];
    }
    const float inv = 1.0f / (N_ * PL_);
    float mu = s1 * inv;
    float var = s2 * inv - mu * mu;
    float m = rsqrtf(var + 1e-5f) * g[pn];
    bnmul[pn] = m;
    bnadd[pn] = bb[pn] - mu * m;
}

// ---------------------------------------------------------------- k_gemm_mfma
// C[M,N] = act(A@W^T + bias), 64x64 tile, BK=32, 4 waves, bf16 MFMA.
// FUSE_BN: apply per-pn (k>>4) affine to A during staging.
template <int ACT, int FUSE_BN>
__global__ void __launch_bounds__(256) k_gemm_mfma(
        const float* __restrict__ A, const float* __restrict__ W,
        const float* __restrict__ bias, const float* __restrict__ bnmul,
        const float* __restrict__ bnadd, float* __restrict__ Cout,
        int M, int Nn, int K) {
    __shared__ unsigned short Ab[64][36];
    __shared__ unsigned short Wb[64][36];
    int bm = blockIdx.x * 64, bn = blockIdx.y * 64;
    int t = threadIdx.x;
    int wid = t >> 6, lane = t & 63, l15 = lane & 15, lg = lane >> 4;
    int srw = t >> 2, sk = (t & 3) * 8;
    f32x4 acc[4];
#pragma unroll
    for (int nt = 0; nt < 4; ++nt) acc[nt] = (f32x4){0.f, 0.f, 0.f, 0.f};

    for (int kt = 0; kt < K; kt += 32) {
        float4 av0 = *(const float4*)(A + (size_t)(bm + srw) * K + kt + sk);
        float4 av1 = *(const float4*)(A + (size_t)(bm + srw) * K + kt + sk + 4);
        float4 wv0 = *(const float4*)(W + (size_t)(bn + srw) * K + kt + sk);
        float4 wv1 = *(const float4*)(W + (size_t)(bn + srw) * K + kt + sk + 4);
        if (FUSE_BN) {
            int pn = (kt + sk) >> 4;
            float m = bnmul[pn], ad = bnadd[pn];
            av0.x = av0.x * m + ad; av0.y = av0.y * m + ad;
            av0.z = av0.z * m + ad; av0.w = av0.w * m + ad;
            av1.x = av1.x * m + ad; av1.y = av1.y * m + ad;
            av1.z = av1.z * m + ad; av1.w = av1.w * m + ad;
        }
        __syncthreads();
        {
            uint4 pk;
            pk.x = (unsigned)f2bf(av0.x) | ((unsigned)f2bf(av0.y) << 16);
            pk.y = (unsigned)f2bf(av0.z) | ((unsigned)f2bf(av0.w) << 16);
            pk.z = (unsigned)f2bf(av1.x) | ((unsigned)f2bf(av1.y) << 16);
            pk.w = (unsigned)f2bf(av1.z) | ((unsigned)f2bf(av1.w) << 16);
            *((uint4_a*)&Ab[srw][sk]) = pk;
            uint4 pw;
            pw.x = (unsigned)f2bf(wv0.x) | ((unsigned)f2bf(wv0.y) << 16);
            pw.y = (unsigned)f2bf(wv0.z) | ((unsigned)f2bf(wv0.w) << 16);
            pw.z = (unsigned)f2bf(wv1.x) | ((unsigned)f2bf(wv1.y) << 16);
            pw.w = (unsigned)f2bf(wv1.z) | ((unsigned)f2bf(wv1.w) << 16);
            *((uint4_a*)&Wb[srw][sk]) = pw;
        }
        __syncthreads();
        bf16x8 af = *((const bf16x8_a*)&Ab[wid * 16 + l15][lg * 8]);
#pragma unroll
        for (int nt = 0; nt < 4; ++nt) {
            bf16x8 wf = *((const bf16x8_a*)&Wb[nt * 16 + l15][lg * 8]);
            acc[nt] = __builtin_amdgcn_mfma_f32_16x16x32_bf16(af, wf, acc[nt], 0, 0, 0);
        }
    }
#pragma unroll
    for (int nt = 0; nt < 4; ++nt) {
#pragma unroll
        for (int r = 0; r < 4; ++r) {
            int m_ = bm + wid * 16 + 4 * lg + r;
            int n_ = bn + nt * 16 + l15;
            float v = acc[nt][r] + bias[n_];
            if (ACT) v = geluf(v);
            Cout[(size_t)m_ * Nn + n_] = v;
        }
    }
}

// ---------------------------------------------------------------- k_rowmlp4
__global__ void k_rowmlp4(const float* __restrict__ g3, const float* __restrict__ W4,
                          const float* __restrict__ b4, float* __restrict__ sxf) {
    int n = blockIdx.x, t = threadIdx.x;  // 128 threads
    __shared__ float row[192];
    for (int j = t; j < 192; j += 128) row[j] = g3[(size_t)n * 192 + j];
    __syncthreads();
    if (t < 96) {
        float a = b4[t];
        const float* wr = W4 + t * 192;
#pragma unroll 4
        for (int j = 0; j < 192; ++j) a += row[j] * wr[j];
        sxf[(size_t)n * 96 + t] = a;
    }
}

// ---------------------------------------------------------------- k_u (+ fused low-pass)
__global__ void k_u(const float* __restrict__ u1, const float* __restrict__ ln1g,
                    const float* __restrict__ ln1b, const float* __restrict__ W6,
                    const float* __restrict__ b6, const float* __restrict__ ln2g,
                    const float* __restrict__ ln2b, const float* __restrict__ W7,
                    const float* __restrict__ b7, float* __restrict__ u2out) {
    int n = blockIdx.x, t = threadIdx.x;  // 192 threads
    __shared__ float a[192];
    __shared__ float red1[256], red2[256];
    __shared__ float c2[48];
    __shared__ float stat[2];
    __shared__ float u3l[96];
    __shared__ float cosb[5][96], sinb[5][96];
    __shared__ float coef[9];
    if (t < 96) {
#pragma unroll
        for (int k = 0; k < 5; ++k) {
            float sv, cv2;
            __sincosf(6.283185307179586f * (float)(k * t) / 96.0f, &sv, &cv2);
            cosb[k][t] = cv2; sinb[k][t] = sv;
        }
    }
    const float* ur = u1 + (size_t)n * 384;
    float av = 0.5f * (ur[2 * t] + ur[2 * t + 1]);
    red1[t] = av; red2[t] = av * av;
    if (t < 64) { red1[192 + t] = 0.f; red2[192 + t] = 0.f; }
    __syncthreads();
    for (int st = 128; st > 0; st >>= 1) {
        if (t < st) { red1[t] += red1[t + st]; red2[t] += red2[t + st]; }
        __syncthreads();
    }
    if (t == 0) {
        float mu = red1[0] * (1.0f / 192.0f);
        float var = red2[0] * (1.0f / 192.0f) - mu * mu;
        stat[0] = mu; stat[1] = rsqrtf(var + 1e-5f);
    }
    __syncthreads();
    a[t] = (av - stat[0]) * stat[1] * ln1g[t] + ln1b[t];
    __syncthreads();
    float bv = 0.f;
    if (t < 96) {
        bv = b6[t];
        const float* wr = W6 + t * 192;
#pragma unroll 4
        for (int j = 0; j < 192; ++j) bv += a[j] * wr[j];
    }
    __syncthreads();
    if (t < 96) red1[t] = bv;
    __syncthreads();
    float cv = 0.f;
    if (t < 48) cv = 0.5f * (red1[2 * t] + red1[2 * t + 1]);
    __syncthreads();
    if (t < 48) { red1[t] = cv; red2[t] = cv * cv; }
    else if (t < 64) { red1[t] = 0.f; red2[t] = 0.f; }
    __syncthreads();
    for (int st = 32; st > 0; st >>= 1) {
        if (t < st) { red1[t] += red1[t + st]; red2[t] += red2[t + st]; }
        __syncthreads();
    }
    if (t == 0) {
        float mu = red1[0] * (1.0f / 48.0f);
        float var = red2[0] * (1.0f / 48.0f) - mu * mu;
        stat[0] = mu; stat[1] = rsqrtf(var + 1e-5f);
    }
    __syncthreads();
    if (t < 48) c2[t] = (cv - stat[0]) * stat[1] * ln2g[t] + ln2b[t];
    __syncthreads();
    if (t < 96) {
        float acc = b7[t];
        const float* wr = W7 + t * 48;
#pragma unroll
        for (int j = 0; j < 48; ++j) acc += c2[j] * wr[j];
        u3l[t] = acc;
    }
    __syncthreads();
    if (t < 9) {
        int k = (t < 5) ? t : t - 4;
        const float* bas = (t < 5) ? cosb[k] : sinb[k];
        float acc = 0.f;
#pragma unroll 4
        for (int m = 0; m < 96; ++m) acc += u3l[m] * bas[m];
        coef[t] = acc;
    }
    __syncthreads();
    if (t < 96) {
        float rec = coef[0];
#pragma unroll
        for (int k = 1; k <= 4; ++k)
            rec += 2.0f * (coef[k] * cosb[k][t] + coef[4 + k] * sinb[k][t]);
        u2out[(size_t)n * 96 + t] = u3l[t] + rec * (1.0f / 96.0f);
    }
}

// ---------------------------------------------------------------- k_conv
__global__ void k_conv(const float* __restrict__ u2, const float* __restrict__ tw,
                       const float* __restrict__ tb, float* __restrict__ u4) {
    int b = blockIdx.x, xq = blockIdx.y, t = threadIdx.x;
    int x0 = xq * 24;
    __shared__ float ub[32][26];
    __shared__ float twl[3072];
    for (int i = t; i < 832; i += 256) {
        int ic = i / 26, xx = i % 26;
        int gx = x0 + xx - 1;
        ub[ic][xx] = (gx >= 0 && gx < 96) ? u2[((size_t)b * 32 + ic) * 96 + gx] : 0.f;
    }
    for (int i = t; i < 3072; i += 256) twl[i] = tw[i];
    __syncthreads();
    for (int i = t; i < 768; i += 256) {
        int oc = i / 24, xx = i % 24;
        float acc = tb[oc];
#pragma unroll 8
        for (int ic = 0; ic < 32; ++ic) {
            const float* wv = twl + (oc * 32 + ic) * 3;
            acc += ub[ic][xx] * wv[0] + ub[ic][xx + 1] * wv[1] + ub[ic][xx + 2] * wv[2];
        }
        u4[((size_t)b * 32 + oc) * 96 + x0 + xx] = ub[oc][xx + 1] + geluf(acc);
    }
}

// ---------------------------------------------------------------- k_out
__global__ void k_out(const float* __restrict__ sxf, const float* __restrict__ u4,
                      const float* __restrict__ W8, const float* __restrict__ b8,
                      float* __restrict__ out) {
    int b = blockIdx.x, oq = blockIdx.y, t = threadIdx.x;
    __shared__ float ld[32][193];
    for (int i = t; i < 32 * 96; i += 256) {
        int c = i / 96, j = i % 96;
        ld[c][j]      = sxf[((size_t)(b * 32 + c)) * 96 + j];
        ld[c][96 + j] = u4[((size_t)(b * 32 + c)) * 96 + j];
    }
    __syncthreads();
    for (int i = t; i < 24 * 32; i += 256) {
        int o = oq * 24 + (i >> 5), c = i & 31;
        float acc = b8[o];
        const float* wr = W8 + o * 192;
#pragma unroll 4
        for (int j = 0; j < 192; ++j) acc += ld[c][j] * wr[j];
        out[((size_t)b * 96 + o) * 32 + c] = acc;
    }
}

// ---------------------------------------------------------------- launch
extern "C" void kernel_launch(void* const* d_in, const int* in_sizes, int n_in,
                              void* d_out, int out_size, void* d_ws, size_t ws_size,
                              hipStream_t stream) {
    const float* s    = (const float*)d_in[0];
    const float* t    = (const float*)d_in[1];
    const int*   cyc  = (const int*)d_in[2];
    const float* rw1  = (const float*)d_in[3];
    const float* rb1  = (const float*)d_in[4];
    const float* rw2  = (const float*)d_in[5];
    const float* rb2  = (const float*)d_in[6];
    const float* A0   = (const float*)d_in[7];
    const float* A1   = (const float*)d_in[8];
    const float* A2   = (const float*)d_in[9];
    const float* P0   = (const float*)d_in[10];
    const float* P1   = (const float*)d_in[11];
    const float* P2   = (const float*)d_in[12];
    const float* Wqkv = (const float*)d_in[13];
    const float* bqkv = (const float*)d_in[14];
    const float* Wo   = (const float*)d_in[15];
    const float* bo   = (const float*)d_in[16];
    const float* alpha= (const float*)d_in[17];
    const float* bn_g = (const float*)d_in[18];
    const float* bn_b = (const float*)d_in[19];
    const float* W3   = (const float*)d_in[20];
    const float* b3   = (const float*)d_in[21];
    const float* W4   = (const float*)d_in[22];
    const float* b4   = (const float*)d_in[23];
    const float* W5   = (const float*)d_in[24];
    const float* b5   = (const float*)d_in[25];
    const float* W6   = (const float*)d_in[26];
    const float* b6   = (const float*)d_in[27];
    const float* W7   = (const float*)d_in[28];
    const float* b7   = (const float*)d_in[29];
    const float* W8   = (const float*)d_in[30];
    const float* b8   = (const float*)d_in[31];
    const float* ln1g = (const float*)d_in[32];
    const float* ln1b = (const float*)d_in[33];
    const float* ln2g = (const float*)d_in[34];
    const float* ln2b = (const float*)d_in[35];
    const float* tew  = (const float*)d_in[36];
    const float* teb  = (const float*)d_in[37];

    float* ws     = (float*)d_ws;
    float* wp     = ws;                         // 192
    float* phis   = ws + 192;                   // 4096
    float* bnpart = ws + 4288;                  // 512
    float* bnmul  = ws + 4800;                  // 64
    float* bnadd  = ws + 4864;                  // 64
    float* srow   = ws + 4928;                  // 1048576
    float* trow   = srow + 1048576;             // 1048576
    float* R      = trow + 1048576;             // overlay region
    // phase 1 overlay
    float* pcs = R;                             // 3145728
    // phase 2 overlay
    float* sx  = R;                             // 2097152
    float* g3  = R + 2097152;                   // 393216
    float* sxf = R + 2490368;                   // 196608
    float* u1  = R + 2686976;                   // 786432
    float* u2f = R + 3473408;                   // 196608
    float* u4f = R + 3670016;                   // 196608
    float* out = (float*)d_out;

    k_headphi<<<64, 256, 0, stream>>>(s, rw1, rb1, rw2, rb2, P0, P1, P2, cyc, wp, phis);
    k_attn_mfma<<<dim3(3, 64), 512, 0, stream>>>(s, cyc, A0, A1, A2, P0, P1, P2, wp, pcs);
    k_combine<<<dim3(64, 16), 256, 0, stream>>>(s, t, pcs, srow, trow);
    k_patch<<<2048, 256, 0, stream>>>(srow, phis, Wqkv, bqkv, Wo, bo, alpha, sx);
    k_bn_stats<<<dim3(64, 4), 256, 0, stream>>>(sx, bnpart);
    k_bn_final<<<1, 64, 0, stream>>>(bnpart, bn_g, bn_b, bnmul, bnadd);
    k_gemm_mfma<1, 1><<<dim3(32, 3), 256, 0, stream>>>(sx, W3, b3, bnmul, bnadd, g3, 2048, 192, 1024);
    k_rowmlp4<<<2048, 128, 0, stream>>>(g3, W4, b4, sxf);
    k_gemm_mfma<0, 0><<<dim3(32, 6), 256, 0, stream>>>(trow, W5, b5, bnmul, bnadd, u1, 2048, 384, 512);
    k_u<<<2048, 192, 0, stream>>>(u1, ln1g, ln1b, W6, b6, ln2g, ln2b, W7, b7, u2f);
    k_conv<<<dim3(64, 4), 256, 0, stream>>>(u2f, tew, teb, u4f);
    k_out<<<dim3(64, 4), 256, 0, stream>>>(sxf, u4f, W8, b8, out);
}

// Round 7
// 341.846 us; speedup vs baseline: 1.3785x; 1.0284x over previous
//
#include <hip/hip_runtime.h>
#include <math.h>

#define B_    64
#define I_    512
#define C_    32
#define PRED_ 96
#define PL_   16
#define ST_   8
#define NH_   8
#define PN_   64
#define N_    2048

typedef short bf16x8 __attribute__((ext_vector_type(8)));
typedef float f32x4 __attribute__((ext_vector_type(4)));
typedef bf16x8 __attribute__((may_alias)) bf16x8_a;
typedef uint2 __attribute__((may_alias)) uint2_a;
typedef uint4 __attribute__((may_alias)) uint4_a;

__device__ __forceinline__ float geluf(float x) {
    return 0.5f * x * (1.0f + erff(x * 0.70710678118654752f));
}
__device__ __forceinline__ float softplusf(float x) {
    return fmaxf(x, 0.0f) + log1pf(__expf(-fabsf(x)));
}
__device__ __forceinline__ unsigned short f2bf(float x) {
    union { float f; unsigned int u; } v; v.f = x;
    unsigned int r = v.u + 0x7fffu + ((v.u >> 16) & 1u);
    return (unsigned short)(r >> 16);
}

// ---------------------------------------------------------------- k_headphi
__global__ void k_headphi(const float* __restrict__ s, const float* __restrict__ rw1,
                          const float* __restrict__ rb1, const float* __restrict__ rw2,
                          const float* __restrict__ rb2,
                          const float* __restrict__ P0, const float* __restrict__ P1,
                          const float* __restrict__ P2, const int* __restrict__ cyc,
                          float* __restrict__ wp, float* __restrict__ phis) {
    int b = blockIdx.x, t = threadIdx.x;
    __shared__ float part[8][32];
    __shared__ float smean[32];
    __shared__ float h[16];
    __shared__ float wpl[3];
    __shared__ float pm[I_];
    int c = t & 31, chunk = t >> 5;
    float acc = 0.f;
    for (int l = chunk * 64; l < chunk * 64 + 64; ++l)
        acc += s[((size_t)b * I_ + l) * C_ + c];
    part[chunk][c] = acc;
    __syncthreads();
    if (t < 32) {
        float v = 0.f;
#pragma unroll
        for (int i = 0; i < 8; ++i) v += part[i][t];
        smean[t] = v * (1.0f / I_);
    }
    __syncthreads();
    if (t < 16) {
        float a = rb1[t];
#pragma unroll
        for (int c2 = 0; c2 < 32; ++c2) a += smean[c2] * rw1[t * 32 + c2];
        h[t] = geluf(a);
    }
    __syncthreads();
    if (t == 0) {
        float lg[3], mx = -1e30f;
        for (int k = 0; k < 3; ++k) {
            float a = rb2[k];
            for (int j = 0; j < 16; ++j) a += h[j] * rw2[k * 16 + j];
            lg[k] = a; mx = fmaxf(mx, a);
        }
        float d = 0.f;
        for (int k = 0; k < 3; ++k) { lg[k] = __expf(lg[k] - mx); d += lg[k]; }
        float inv = 1.f / d;
        for (int k = 0; k < 3; ++k) { wpl[k] = lg[k] * inv; wp[b * 3 + k] = lg[k] * inv; }
    }
    __syncthreads();
    float p0 = wpl[0], p1 = wpl[1], p2 = wpl[2];
    int cy = cyc[b];
    for (int l = t; l < I_; l += 256) {
        float acc2 = 0.f;
        {
            int idx = (cy + l) % 24;
            const float4* r = (const float4*)(P0 + idx * 32);
            float s4 = 0.f;
#pragma unroll
            for (int i = 0; i < 8; ++i) { float4 v = r[i]; s4 += v.x + v.y + v.z + v.w; }
            acc2 += p0 * s4;
        }
        {
            int idx = (cy + l) % 168;
            const float4* r = (const float4*)(P1 + idx * 32);
            float s4 = 0.f;
#pragma unroll
            for (int i = 0; i < 8; ++i) { float4 v = r[i]; s4 += v.x + v.y + v.z + v.w; }
            acc2 += p1 * s4;
        }
        {
            int idx = (cy + l) % 336;
            const float4* r = (const float4*)(P2 + idx * 32);
            float s4 = 0.f;
#pragma unroll
            for (int i = 0; i < 8; ++i) { float4 v = r[i]; s4 += v.x + v.y + v.z + v.w; }
            acc2 += p2 * s4;
        }
        pm[l] = acc2 * (1.0f / 32.0f);
    }
    __syncthreads();
    if (t < PN_) {
        float sum = 0.f;
#pragma unroll
        for (int j = 0; j < 16; ++j) {
            int l = t * ST_ + j; if (l > 511) l = 511;
            sum += pm[l];
        }
        phis[b * PN_ + t] = sum * (1.0f / 16.0f);
    }
}

// ---------------------------------------------------------------- k_attn_mfma
__global__ void __launch_bounds__(512) k_attn_mfma(
        const float* __restrict__ s, const int* __restrict__ cyc,
        const float* __restrict__ A0, const float* __restrict__ A1, const float* __restrict__ A2,
        const float* __restrict__ P0, const float* __restrict__ P1, const float* __restrict__ P2,
        const float* __restrict__ wp, float* __restrict__ pcs) {
    int k3 = blockIdx.x, b = blockIdx.y;
    int t = threadIdx.x;
    int wid = t >> 6, lane = t & 63;
    int l15 = lane & 15, lg = lane >> 4;

    __shared__ unsigned short s_lds[512][40];
    __shared__ unsigned short sT[32][520];
    __shared__ unsigned short Pt[8][64][40];

    {
        int row = t;
        const float4* src = (const float4*)(s + ((size_t)b * I_ + row) * C_);
        unsigned short bv[32];
#pragma unroll
        for (int i = 0; i < 8; ++i) {
            float4 v = src[i];
            bv[4 * i + 0] = f2bf(v.x); bv[4 * i + 1] = f2bf(v.y);
            bv[4 * i + 2] = f2bf(v.z); bv[4 * i + 3] = f2bf(v.w);
        }
#pragma unroll
        for (int i = 0; i < 4; ++i) {
            uint4 pk;
            pk.x = (unsigned)bv[8 * i + 0] | ((unsigned)bv[8 * i + 1] << 16);
            pk.y = (unsigned)bv[8 * i + 2] | ((unsigned)bv[8 * i + 3] << 16);
            pk.z = (unsigned)bv[8 * i + 4] | ((unsigned)bv[8 * i + 5] << 16);
            pk.w = (unsigned)bv[8 * i + 6] | ((unsigned)bv[8 * i + 7] << 16);
            *((uint4_a*)&s_lds[row][8 * i]) = pk;
        }
#pragma unroll
        for (int cc = 0; cc < 32; ++cc) sT[cc][row] = bv[cc];
    }

    const float* Atab; const float* Ptab; int Wk;
    if (k3 == 0)      { Atab = A0; Ptab = P0; Wk = 24;  }
    else if (k3 == 1) { Atab = A1; Ptab = P1; Wk = 168; }
    else              { Atab = A2; Ptab = P2; Wk = 336; }
    float wpv = wp[b * 3 + k3];
    int cy = cyc[b];
    bf16x8 qrf[4];
#pragma unroll
    for (int qt = 0; qt < 4; ++qt) {
        int q = wid * 64 + qt * 16 + l15;
        int idx = (cy + q) % Wk;
        const float4* Ar = (const float4*)(Atab + idx * 32 + lg * 8);
        const float4* Pr = (const float4*)(Ptab + idx * 32 + lg * 8);
        float4 a0 = Ar[0], a1 = Ar[1], p0 = Pr[0], p1 = Pr[1];
        float qv[8];
        qv[0] = softplusf(a0.x) * __cosf(p0.x);
        qv[1] = softplusf(a0.y) * __cosf(p0.y);
        qv[2] = softplusf(a0.z) * __cosf(p0.z);
        qv[3] = softplusf(a0.w) * __cosf(p0.w);
        qv[4] = softplusf(a1.x) * __cosf(p1.x);
        qv[5] = softplusf(a1.y) * __cosf(p1.y);
        qv[6] = softplusf(a1.z) * __cosf(p1.z);
        qv[7] = softplusf(a1.w) * __cosf(p1.w);
        bf16x8 f;
#pragma unroll
        for (int j = 0; j < 8; ++j) f[j] = (short)f2bf(qv[j]);
        qrf[qt] = f;
    }
    __syncthreads();

    const float rs = 0.17677669529663687f;
    f32x4 acc[4][2];
#pragma unroll
    for (int qt = 0; qt < 4; ++qt)
#pragma unroll
        for (int ct = 0; ct < 2; ++ct) acc[qt][ct] = (f32x4){0.f, 0.f, 0.f, 0.f};
    float dacc[4] = {0.f, 0.f, 0.f, 0.f};

    for (int kc = 0; kc < 16; ++kc) {
        int key0 = kc * 32;
        bf16x8 a0 = *((const bf16x8_a*)&s_lds[key0 + l15][lg * 8]);
        bf16x8 a1 = *((const bf16x8_a*)&s_lds[key0 + 16 + l15][lg * 8]);
        f32x4 stv[4][2];
#pragma unroll
        for (int qt = 0; qt < 4; ++qt) {
            stv[qt][0] = __builtin_amdgcn_mfma_f32_16x16x32_bf16(a0, qrf[qt], (f32x4){0.f,0.f,0.f,0.f}, 0, 0, 0);
            stv[qt][1] = __builtin_amdgcn_mfma_f32_16x16x32_bf16(a1, qrf[qt], (f32x4){0.f,0.f,0.f,0.f}, 0, 0, 0);
        }
#pragma unroll
        for (int qt = 0; qt < 4; ++qt) {
#pragma unroll
            for (int h = 0; h < 2; ++h) {
                unsigned short pb[4];
                float ds = 0.f;
#pragma unroll
                for (int r = 0; r < 4; ++r) {
                    float e = __expf(stv[qt][h][r] * rs);
                    unsigned short ub = f2bf(e);
                    pb[r] = ub;
                    union { unsigned int u; float f; } bb; bb.u = ((unsigned int)ub) << 16;
                    ds += bb.f;
                }
                dacc[qt] += ds;
                uint2 w2;
                w2.x = (unsigned)pb[0] | ((unsigned)pb[1] << 16);
                w2.y = (unsigned)pb[2] | ((unsigned)pb[3] << 16);
                *((uint2_a*)&Pt[wid][qt * 16 + l15][h * 16 + lg * 4]) = w2;
            }
        }
        bf16x8 b0 = *((const bf16x8_a*)&sT[l15][key0 + lg * 8]);
        bf16x8 b1 = *((const bf16x8_a*)&sT[16 + l15][key0 + lg * 8]);
#pragma unroll
        for (int qt = 0; qt < 4; ++qt) {
            bf16x8 pa = *((const bf16x8_a*)&Pt[wid][qt * 16 + l15][lg * 8]);
            acc[qt][0] = __builtin_amdgcn_mfma_f32_16x16x32_bf16(pa, b0, acc[qt][0], 0, 0, 0);
            acc[qt][1] = __builtin_amdgcn_mfma_f32_16x16x32_bf16(pa, b1, acc[qt][1], 0, 0, 0);
        }
    }

#pragma unroll
    for (int qt = 0; qt < 4; ++qt) {
        float dq = dacc[qt];
        dq += __shfl_xor(dq, 16);
        dq += __shfl_xor(dq, 32);
        float invd[4];
#pragma unroll
        for (int r = 0; r < 4; ++r) {
            float dr = __shfl(dq, 4 * lg + r);
            invd[r] = wpv / dr;
        }
        int qbase = wid * 64 + qt * 16 + 4 * lg;
#pragma unroll
        for (int ct = 0; ct < 2; ++ct) {
            int c = ct * 16 + l15;
            float4 o;
            o.x = acc[qt][ct][0] * invd[0];
            o.y = acc[qt][ct][1] * invd[1];
            o.z = acc[qt][ct][2] * invd[2];
            o.w = acc[qt][ct][3] * invd[3];
            *(float4*)(pcs + (((size_t)k3 * B_ + b) * C_ + c) * I_ + qbase) = o;
        }
    }
}

// ---------------------------------------------------------------- k_combine (srow only)
__global__ void k_combine(const float* __restrict__ s, const float* __restrict__ pcs,
                          float* __restrict__ srow) {
    int b = blockIdx.x, l0 = blockIdx.y * 32;
    int tt_ = threadIdx.x;
    __shared__ float st[32][33];
#pragma unroll
    for (int r = 0; r < 4; ++r) {
        int lin = r * 256 + tt_;
        int lq = lin >> 5, c = lin & 31;
        st[lq][c] = s[((size_t)b * I_ + l0 + lq) * C_ + c];
    }
    __syncthreads();
    const size_t CH = (size_t)B_ * C_ * I_;
#pragma unroll
    for (int r = 0; r < 4; ++r) {
        int lin = r * 256 + tt_;
        int co = lin >> 5, lo = lin & 31;
        size_t pi = ((size_t)b * C_ + co) * I_ + l0 + lo;
        float sum = pcs[pi] + pcs[CH + pi] + pcs[2 * CH + pi];
        srow[pi] = st[lo][co] + sum;
    }
}

// ---------------------------------------------------------------- k_patch (v3, MFMA)
// qkv projection + rank-4 score (qk + cos-bias) via 16x16x32 bf16 MFMA.
// Score MFMA swapped (A=key-side, B=query-side) -> D[s][p]; exp + PV in fp32 VALU.
__global__ void __launch_bounds__(256) k_patch(
        const float* __restrict__ srow, const float* __restrict__ phis,
        const float* __restrict__ Wqkv, const float* __restrict__ bqkv,
        const float* __restrict__ Wo, const float* __restrict__ bo,
        const float* __restrict__ alpha_p, float* __restrict__ sx) {
    int n = blockIdx.x, t = threadIdx.x;
    int p = t & 63, w = t >> 6;
    int lane = t & 63, l15 = lane & 15, lg = lane >> 4;
    int b = n >> 5;
    __shared__ float spl[64][17];               // fp32 sp (residual)
    __shared__ unsigned short spb[64][16];      // bf16 sp
    __shared__ unsigned short wqb[48][16];      // bf16 Wqkv
    // rows 0-15: q*rs2, 16-31: k, 32: cos, 33: sin, 34: a*cos, 35: a*sin
    __shared__ unsigned short qkv2[36][72];
    __shared__ float vlf[16][68];               // fp32 v rows
    __shared__ float o2l[64][18];
    __shared__ float wo[16][16];
    const float rs2 = 0.70710678118654752f;

    float alpha = alpha_p[0];
    const float* srn = srow + (size_t)n * I_;
#pragma unroll
    for (int jj = 0; jj < 4; ++jj) {
        int j = w * 4 + jj;
        int l = p * ST_ + j; if (l > 511) l = 511;
        float v = srn[l];
        spl[p][j] = v; spb[p][j] = f2bf(v);
    }
    for (int i = t; i < 768; i += 256) wqb[i >> 4][i & 15] = f2bf(Wqkv[i]);
    wo[t >> 4][t & 15] = Wo[t];
    if (t < 64) {
        float sv, cv;
        __sincosf(phis[b * PN_ + t], &sv, &cv);
        qkv2[32][t] = f2bf(cv); qkv2[33][t] = f2bf(sv);
        qkv2[34][t] = f2bf(alpha * cv); qkv2[35][t] = f2bf(alpha * sv);
    }
    __syncthreads();

    // projection: wave w -> patches w*16..w*16+15; loop 3 output tiles
    {
        bf16x8 af = {};
        if (lg < 2) af = *((const bf16x8_a*)&spb[w * 16 + l15][lg * 8]);
        f32x4 pacc[3];
#pragma unroll
        for (int nt = 0; nt < 3; ++nt) {
            bf16x8 wf = {};
            if (lg < 2) wf = *((const bf16x8_a*)&wqb[nt * 16 + l15][lg * 8]);
            pacc[nt] = __builtin_amdgcn_mfma_f32_16x16x32_bf16(af, wf, (f32x4){0.f,0.f,0.f,0.f}, 0, 0, 0);
        }
        __syncthreads();  // everyone done reading spb/wqb before qkv2 writes? (distinct arrays, but sync for o2l reuse safety)
#pragma unroll
        for (int nt = 0; nt < 3; ++nt) {
            int o = nt * 16 + l15;
            float bias = bqkv[o];
            float v0 = pacc[nt][0] + bias, v1 = pacc[nt][1] + bias;
            float v2 = pacc[nt][2] + bias, v3 = pacc[nt][3] + bias;
            int pb_ = w * 16 + 4 * lg;
            if (o < 16) {
                v0 *= rs2; v1 *= rs2; v2 *= rs2; v3 *= rs2;
                uint2 w2;
                w2.x = (unsigned)f2bf(v0) | ((unsigned)f2bf(v1) << 16);
                w2.y = (unsigned)f2bf(v2) | ((unsigned)f2bf(v3) << 16);
                *((uint2_a*)&qkv2[o][pb_]) = w2;
            } else if (o < 32) {
                uint2 w2;
                w2.x = (unsigned)f2bf(v0) | ((unsigned)f2bf(v1) << 16);
                w2.y = (unsigned)f2bf(v2) | ((unsigned)f2bf(v3) << 16);
                *((uint2_a*)&qkv2[o][pb_]) = w2;
            } else {
                *(float4*)&vlf[o - 32][pb_] = make_float4(v0, v1, v2, v3);
            }
        }
    }
    __syncthreads();

    // scores + PV: wave w handles heads 2w, 2w+1
#pragma unroll
    for (int hh = 0; hh < 2; ++hh) {
        int h = 2 * w + hh;
        bf16x8 qf[4];
#pragma unroll
        for (int pt = 0; pt < 4; ++pt) {
            bf16x8 f = {};
            if (lg == 0) {
                int col = pt * 16 + l15;
                f[0] = (short)qkv2[2 * h][col];
                f[1] = (short)qkv2[2 * h + 1][col];
                f[2] = (short)qkv2[34][col];
                f[3] = (short)qkv2[35][col];
            }
            qf[pt] = f;
        }
        float o0a[4] = {0.f,0.f,0.f,0.f}, o1a[4] = {0.f,0.f,0.f,0.f}, da[4] = {0.f,0.f,0.f,0.f};
#pragma unroll
        for (int st = 0; st < 4; ++st) {
            bf16x8 kf = {};
            if (lg == 0) {
                int col = st * 16 + l15;
                kf[0] = (short)qkv2[16 + 2 * h][col];
                kf[1] = (short)qkv2[17 + 2 * h][col];
                kf[2] = (short)qkv2[32][col];
                kf[3] = (short)qkv2[33][col];
            }
            float4 v0 = *(const float4*)&vlf[2 * h][st * 16 + 4 * lg];
            float4 v1 = *(const float4*)&vlf[2 * h + 1][st * 16 + 4 * lg];
#pragma unroll
            for (int pt = 0; pt < 4; ++pt) {
                f32x4 sv = __builtin_amdgcn_mfma_f32_16x16x32_bf16(kf, qf[pt], (f32x4){0.f,0.f,0.f,0.f}, 0, 0, 0);
                float e0 = __expf(sv[0]), e1 = __expf(sv[1]);
                float e2 = __expf(sv[2]), e3 = __expf(sv[3]);
                da[pt] += e0 + e1 + e2 + e3;
                o0a[pt] += e0 * v0.x + e1 * v0.y + e2 * v0.z + e3 * v0.w;
                o1a[pt] += e0 * v1.x + e1 * v1.y + e2 * v1.z + e3 * v1.w;
            }
        }
#pragma unroll
        for (int pt = 0; pt < 4; ++pt) {
            float o0 = o0a[pt], o1 = o1a[pt], dd = da[pt];
            o0 += __shfl_xor(o0, 16); o0 += __shfl_xor(o0, 32);
            o1 += __shfl_xor(o1, 16); o1 += __shfl_xor(o1, 32);
            dd += __shfl_xor(dd, 16); dd += __shfl_xor(dd, 32);
            if (lg == 0) {
                float inv = 1.f / dd;
                *(float2*)&o2l[pt * 16 + l15][2 * h] = make_float2(o0 * inv, o1 * inv);
            }
        }
    }
    __syncthreads();

    float* sxr = sx + ((size_t)n * PN_ + p) * PL_;
#pragma unroll
    for (int ii = 0; ii < 4; ++ii) {
        int i2 = w * 4 + ii;
        float a = bo[i2];
#pragma unroll
        for (int j = 0; j < 16; ++j) a += o2l[p][j] * wo[i2][j];
        sxr[i2] = geluf(spl[p][i2] + a);
    }
}

// ---------------------------------------------------------------- k_bn_stats
__global__ void k_bn_stats(const float* __restrict__ sx, float* __restrict__ bnpart) {
    int pn = blockIdx.x, chunk = blockIdx.y, t = threadIdx.x;
    __shared__ float r1[256], r2[256];
    int j4 = t & 3, nb = t >> 2;
    float s1 = 0.f, s2 = 0.f;
    for (int i = 0; i < 8; ++i) {
        int n = chunk * 512 + nb + i * 64;
        float4 v = *(const float4*)(sx + ((size_t)n * PN_ + pn) * PL_ + j4 * 4);
        s1 += v.x + v.y + v.z + v.w;
        s2 += v.x * v.x + v.y * v.y + v.z * v.z + v.w * v.w;
    }
    r1[t] = s1; r2[t] = s2;
    __syncthreads();
    for (int st = 128; st > 0; st >>= 1) {
        if (t < st) { r1[t] += r1[t + st]; r2[t] += r2[t + st]; }
        __syncthreads();
    }
    if (t == 0) {
        bnpart[(pn * 4 + chunk) * 2 + 0] = r1[0];
        bnpart[(pn * 4 + chunk) * 2 + 1] = r2[0];
    }
}

// ---------------------------------------------------------------- k_gemm_mfma
// C[M,N] = act(A@W^T + bias); 64x64 tile, BK=32, bf16 MFMA.
// FUSE_BN: per-pn affine on A (coeffs computed in-block from bnpart).
// TRANS: A is t (B,I,C); logical A[n][l] = t[n>>5][l][n&31].
template <int ACT, int FUSE_BN, int TRANS>
__global__ void __launch_bounds__(256) k_gemm_mfma(
        const float* __restrict__ A, const float* __restrict__ W,
        const float* __restrict__ bias, const float* __restrict__ bnpart,
        const float* __restrict__ bng, const float* __restrict__ bnb,
        float* __restrict__ Cout, int M, int Nn, int K) {
    __shared__ unsigned short Ab[64][36];
    __shared__ unsigned short Wb[64][36];
    __shared__ float bnm[64], bna[64];
    int bm = blockIdx.x * 64, bn = blockIdx.y * 64;
    int t = threadIdx.x;
    int wid = t >> 6, lane = t & 63, l15 = lane & 15, lg = lane >> 4;
    int srw = t >> 2, sk = (t & 3) * 8;
    if (FUSE_BN && t < 64) {
        float s1 = 0.f, s2 = 0.f;
#pragma unroll
        for (int ch = 0; ch < 4; ++ch) {
            s1 += bnpart[(t * 4 + ch) * 2 + 0];
            s2 += bnpart[(t * 4 + ch) * 2 + 1];
        }
        const float inv = 1.0f / (N_ * PL_);
        float mu = s1 * inv;
        float var = s2 * inv - mu * mu;
        float m = rsqrtf(var + 1e-5f) * bng[t];
        bnm[t] = m; bna[t] = bnb[t] - mu * m;
    }
    if (FUSE_BN) __syncthreads();
    f32x4 acc[4];
#pragma unroll
    for (int nt = 0; nt < 4; ++nt) acc[nt] = (f32x4){0.f, 0.f, 0.f, 0.f};

    for (int kt = 0; kt < K; kt += 32) {
        float4 av0, av1;
        if (TRANS) {
            int nrow = bm + srw;
            const float* tp = A + (size_t)(nrow >> 5) * (I_ * C_) + (nrow & 31);
            int l0 = kt + sk;
            av0.x = tp[(size_t)(l0 + 0) * C_]; av0.y = tp[(size_t)(l0 + 1) * C_];
            av0.z = tp[(size_t)(l0 + 2) * C_]; av0.w = tp[(size_t)(l0 + 3) * C_];
            av1.x = tp[(size_t)(l0 + 4) * C_]; av1.y = tp[(size_t)(l0 + 5) * C_];
            av1.z = tp[(size_t)(l0 + 6) * C_]; av1.w = tp[(size_t)(l0 + 7) * C_];
        } else {
            av0 = *(const float4*)(A + (size_t)(bm + srw) * K + kt + sk);
            av1 = *(const float4*)(A + (size_t)(bm + srw) * K + kt + sk + 4);
        }
        float4 wv0 = *(const float4*)(W + (size_t)(bn + srw) * K + kt + sk);
        float4 wv1 = *(const float4*)(W + (size_t)(bn + srw) * K + kt + sk + 4);
        if (FUSE_BN) {
            int pn = (kt + sk) >> 4;
            float m = bnm[pn], ad = bna[pn];
            av0.x = av0.x * m + ad; av0.y = av0.y * m + ad;
            av0.z = av0.z * m + ad; av0.w = av0.w * m + ad;
            av1.x = av1.x * m + ad; av1.y = av1.y * m + ad;
            av1.z = av1.z * m + ad; av1.w = av1.w * m + ad;
        }
        __syncthreads();
        {
            uint4 pk;
            pk.x = (unsigned)f2bf(av0.x) | ((unsigned)f2bf(av0.y) << 16);
            pk.y = (unsigned)f2bf(av0.z) | ((unsigned)f2bf(av0.w) << 16);
            pk.z = (unsigned)f2bf(av1.x) | ((unsigned)f2bf(av1.y) << 16);
            pk.w = (unsigned)f2bf(av1.z) | ((unsigned)f2bf(av1.w) << 16);
            *((uint4_a*)&Ab[srw][sk]) = pk;
            uint4 pw;
            pw.x = (unsigned)f2bf(wv0.x) | ((unsigned)f2bf(wv0.y) << 16);
            pw.y = (unsigned)f2bf(wv0.z) | ((unsigned)f2bf(wv0.w) << 16);
            pw.z = (unsigned)f2bf(wv1.x) | ((unsigned)f2bf(wv1.y) << 16);
            pw.w = (unsigned)f2bf(wv1.z) | ((unsigned)f2bf(wv1.w) << 16);
            *((uint4_a*)&Wb[srw][sk]) = pw;
        }
        __syncthreads();
        bf16x8 af = *((const bf16x8_a*)&Ab[wid * 16 + l15][lg * 8]);
#pragma unroll
        for (int nt = 0; nt < 4; ++nt) {
            bf16x8 wf = *((const bf16x8_a*)&Wb[nt * 16 + l15][lg * 8]);
            acc[nt] = __builtin_amdgcn_mfma_f32_16x16x32_bf16(af, wf, acc[nt], 0, 0, 0);
        }
    }
#pragma unroll
    for (int nt = 0; nt < 4; ++nt) {
#pragma unroll
        for (int r = 0; r < 4; ++r) {
            int m_ = bm + wid * 16 + 4 * lg + r;
            int n_ = bn + nt * 16 + l15;
            float v = acc[nt][r] + bias[n_];
            if (ACT) v = geluf(v);
            Cout[(size_t)m_ * Nn + n_] = v;
        }
    }
}

// ---------------------------------------------------------------- k_rowmlp4
__global__ void k_rowmlp4(const float* __restrict__ g3, const float* __restrict__ W4,
                          const float* __restrict__ b4, float* __restrict__ sxf) {
    int n = blockIdx.x, t = threadIdx.x;  // 128 threads
    __shared__ float row[192];
    for (int j = t; j < 192; j += 128) row[j] = g3[(size_t)n * 192 + j];
    __syncthreads();
    if (t < 96) {
        float a = b4[t];
        const float* wr = W4 + t * 192;
#pragma unroll 4
        for (int j = 0; j < 192; ++j) a += row[j] * wr[j];
        sxf[(size_t)n * 96 + t] = a;
    }
}

// ---------------------------------------------------------------- k_u (+ fused low-pass)
__global__ void k_u(const float* __restrict__ u1, const float* __restrict__ ln1g,
                    const float* __restrict__ ln1b, const float* __restrict__ W6,
                    const float* __restrict__ b6, const float* __restrict__ ln2g,
                    const float* __restrict__ ln2b, const float* __restrict__ W7,
                    const float* __restrict__ b7, float* __restrict__ u2out) {
    int n = blockIdx.x, t = threadIdx.x;  // 192 threads
    __shared__ float a[192];
    __shared__ float red1[256], red2[256];
    __shared__ float c2[48];
    __shared__ float stat[2];
    __shared__ float u3l[96];
    __shared__ float cosb[5][96], sinb[5][96];
    __shared__ float coef[9];
    if (t < 96) {
#pragma unroll
        for (int k = 0; k < 5; ++k) {
            float sv, cv2;
            __sincosf(6.283185307179586f * (float)(k * t) / 96.0f, &sv, &cv2);
            cosb[k][t] = cv2; sinb[k][t] = sv;
        }
    }
    const float* ur = u1 + (size_t)n * 384;
    float av = 0.5f * (ur[2 * t] + ur[2 * t + 1]);
    red1[t] = av; red2[t] = av * av;
    if (t < 64) { red1[192 + t] = 0.f; red2[192 + t] = 0.f; }
    __syncthreads();
    for (int st = 128; st > 0; st >>= 1) {
        if (t < st) { red1[t] += red1[t + st]; red2[t] += red2[t + st]; }
        __syncthreads();
    }
    if (t == 0) {
        float mu = red1[0] * (1.0f / 192.0f);
        float var = red2[0] * (1.0f / 192.0f) - mu * mu;
        stat[0] = mu; stat[1] = rsqrtf(var + 1e-5f);
    }
    __syncthreads();
    a[t] = (av - stat[0]) * stat[1] * ln1g[t] + ln1b[t];
    __syncthreads();
    float bv = 0.f;
    if (t < 96) {
        bv = b6[t];
        const float* wr = W6 + t * 192;
#pragma unroll 4
        for (int j = 0; j < 192; ++j) bv += a[j] * wr[j];
    }
    __syncthreads();
    if (t < 96) red1[t] = bv;
    __syncthreads();
    float cv = 0.f;
    if (t < 48) cv = 0.5f * (red1[2 * t] + red1[2 * t + 1]);
    __syncthreads();
    if (t < 48) { red1[t] = cv; red2[t] = cv * cv; }
    else if (t < 64) { red1[t] = 0.f; red2[t] = 0.f; }
    __syncthreads();
    for (int st = 32; st > 0; st >>= 1) {
        if (t < st) { red1[t] += red1[t + st]; red2[t] += red2[t + st]; }
        __syncthreads();
    }
    if (t == 0) {
        float mu = red1[0] * (1.0f / 48.0f);
        float var = red2[0] * (1.0f / 48.0f) - mu * mu;
        stat[0] = mu; stat[1] = rsqrtf(var + 1e-5f);
    }
    __syncthreads();
    if (t < 48) c2[t] = (cv - stat[0]) * stat[1] * ln2g[t] + ln2b[t];
    __syncthreads();
    if (t < 96) {
        float acc = b7[t];
        const float* wr = W7 + t * 48;
#pragma unroll
        for (int j = 0; j < 48; ++j) acc += c2[j] * wr[j];
        u3l[t] = acc;
    }
    __syncthreads();
    if (t < 9) {
        int k = (t < 5) ? t : t - 4;
        const float* bas = (t < 5) ? cosb[k] : sinb[k];
        float acc = 0.f;
#pragma unroll 4
        for (int m = 0; m < 96; ++m) acc += u3l[m] * bas[m];
        coef[t] = acc;
    }
    __syncthreads();
    if (t < 96) {
        float rec = coef[0];
#pragma unroll
        for (int k = 1; k <= 4; ++k)
            rec += 2.0f * (coef[k] * cosb[k][t] + coef[4 + k] * sinb[k][t]);
        u2out[(size_t)n * 96 + t] = u3l[t] + rec * (1.0f / 96.0f);
    }
}

// ---------------------------------------------------------------- k_conv
__global__ void k_conv(const float* __restrict__ u2, const float* __restrict__ tw,
                       const float* __restrict__ tb, float* __restrict__ u4) {
    int b = blockIdx.x, xq = blockIdx.y, t = threadIdx.x;
    int x0 = xq * 24;
    __shared__ float ub[32][26];
    __shared__ float twl[3072];
    for (int i = t; i < 832; i += 256) {
        int ic = i / 26, xx = i % 26;
        int gx = x0 + xx - 1;
        ub[ic][xx] = (gx >= 0 && gx < 96) ? u2[((size_t)b * 32 + ic) * 96 + gx] : 0.f;
    }
    for (int i = t; i < 3072; i += 256) twl[i] = tw[i];
    __syncthreads();
    for (int i = t; i < 768; i += 256) {
        int oc = i / 24, xx = i % 24;
        float acc = tb[oc];
#pragma unroll 8
        for (int ic = 0; ic < 32; ++ic) {
            const float* wv = twl + (oc * 32 + ic) * 3;
            acc += ub[ic][xx] * wv[0] + ub[ic][xx + 1] * wv[1] + ub[ic][xx + 2] * wv[2];
        }
        u4[((size_t)b * 32 + oc) * 96 + x0 + xx] = ub[oc][xx + 1] + geluf(acc);
    }
}

// ---------------------------------------------------------------- k_out
__global__ void k_out(const float* __restrict__ sxf, const float* __restrict__ u4,
                      const float* __restrict__ W8, const float* __restrict__ b8,
                      float* __restrict__ out) {
    int b = blockIdx.x, oq = blockIdx.y, t = threadIdx.x;
    __shared__ float ld[32][193];
    for (int i = t; i < 32 * 96; i += 256) {
        int c = i / 96, j = i % 96;
        ld[c][j]      = sxf[((size_t)(b * 32 + c)) * 96 + j];
        ld[c][96 + j] = u4[((size_t)(b * 32 + c)) * 96 + j];
    }
    __syncthreads();
    for (int i = t; i < 24 * 32; i += 256) {
        int o = oq * 24 + (i >> 5), c = i & 31;
        float acc = b8[o];
        const float* wr = W8 + o * 192;
#pragma unroll 4
        for (int j = 0; j < 192; ++j) acc += ld[c][j] * wr[j];
        out[((size_t)b * 96 + o) * 32 + c] = acc;
    }
}

// ---------------------------------------------------------------- launch
extern "C" void kernel_launch(void* const* d_in, const int* in_sizes, int n_in,
                              void* d_out, int out_size, void* d_ws, size_t ws_size,
                              hipStream_t stream) {
    const float* s    = (const float*)d_in[0];
    const float* t    = (const float*)d_in[1];
    const int*   cyc  = (const int*)d_in[2];
    const float* rw1  = (const float*)d_in[3];
    const float* rb1  = (const float*)d_in[4];
    const float* rw2  = (const float*)d_in[5];
    const float* rb2  = (const float*)d_in[6];
    const float* A0   = (const float*)d_in[7];
    const float* A1   = (const float*)d_in[8];
    const float* A2   = (const float*)d_in[9];
    const float* P0   = (const float*)d_in[10];
    const float* P1   = (const float*)d_in[11];
    const float* P2   = (const float*)d_in[12];
    const float* Wqkv = (const float*)d_in[13];
    const float* bqkv = (const float*)d_in[14];
    const float* Wo   = (const float*)d_in[15];
    const float* bo   = (const float*)d_in[16];
    const float* alpha= (const float*)d_in[17];
    const float* bn_g = (const float*)d_in[18];
    const float* bn_b = (const float*)d_in[19];
    const float* W3   = (const float*)d_in[20];
    const float* b3   = (const float*)d_in[21];
    const float* W4   = (const float*)d_in[22];
    const float* b4   = (const float*)d_in[23];
    const float* W5   = (const float*)d_in[24];
    const float* b5   = (const float*)d_in[25];
    const float* W6   = (const float*)d_in[26];
    const float* b6   = (const float*)d_in[27];
    const float* W7   = (const float*)d_in[28];
    const float* b7   = (const float*)d_in[29];
    const float* W8   = (const float*)d_in[30];
    const float* b8   = (const float*)d_in[31];
    const float* ln1g = (const float*)d_in[32];
    const float* ln1b = (const float*)d_in[33];
    const float* ln2g = (const float*)d_in[34];
    const float* ln2b = (const float*)d_in[35];
    const float* tew  = (const float*)d_in[36];
    const float* teb  = (const float*)d_in[37];

    float* ws     = (float*)d_ws;
    float* wp     = ws;                         // 192
    float* phis   = ws + 192;                   // 4096
    float* bnpart = ws + 4288;                  // 512
    float* srow   = ws + 4800;                  // 1048576
    float* R      = srow + 1048576;             // overlay region
    // phase 1 overlay
    float* pcs = R;                             // 3145728
    // phase 2 overlay
    float* sx  = R;                             // 2097152
    float* g3  = R + 2097152;                   // 393216
    float* sxf = R + 2490368;                   // 196608
    float* u1  = R + 2686976;                   // 786432
    float* u2f = R + 3473408;                   // 196608
    float* u4f = R + 3670016;                   // 196608
    float* out = (float*)d_out;

    k_headphi<<<64, 256, 0, stream>>>(s, rw1, rb1, rw2, rb2, P0, P1, P2, cyc, wp, phis);
    k_attn_mfma<<<dim3(3, 64), 512, 0, stream>>>(s, cyc, A0, A1, A2, P0, P1, P2, wp, pcs);
    k_combine<<<dim3(64, 16), 256, 0, stream>>>(s, pcs, srow);
    k_patch<<<2048, 256, 0, stream>>>(srow, phis, Wqkv, bqkv, Wo, bo, alpha, sx);
    k_bn_stats<<<dim3(64, 4), 256, 0, stream>>>(sx, bnpart);
    k_gemm_mfma<1, 1, 0><<<dim3(32, 3), 256, 0, stream>>>(sx, W3, b3, bnpart, bn_g, bn_b, g3, 2048, 192, 1024);
    k_rowmlp4<<<2048, 128, 0, stream>>>(g3, W4, b4, sxf);
    k_gemm_mfma<0, 0, 1><<<dim3(32, 6), 256, 0, stream>>>(t, W5, b5, bnpart, bn_g, bn_b, u1, 2048, 384, 512);
    k_u<<<2048, 192, 0, stream>>>(u1, ln1g, ln1b, W6, b6, ln2g, ln2b, W7, b7, u2f);
    k_conv<<<dim3(64, 4), 256, 0, stream>>>(u2f, tew, teb, u4f);
    k_out<<<dim3(64, 4), 256, 0, stream>>>(sxf, u4f, W8, b8, out);
}